// Round 3
// baseline (841.265 us; speedup 1.0000x reference)
//
#include <hip/hip_runtime.h>
#include <stdint.h>

#define SS 2048
#define DD 768
#define HH 12
#define HDIM 64
#define FFD 3072
#define MROWS 4096  // B*S

typedef __bf16 bf16_t;
using bf16x4 = __attribute__((ext_vector_type(4))) __bf16;
using bf16x8 = __attribute__((ext_vector_type(8))) __bf16;
using f32x4  = __attribute__((ext_vector_type(4))) float;

__device__ inline float b2f(bf16_t v) { return (float)v; }
__device__ inline bf16_t f2b(float v) { return (bf16_t)v; }

// native v_exp_f32 (2^x). NOTE: __exp2f is NOT a HIP device intrinsic (glibc
// macro collision at compile time) — must use the amdgcn builtin.
__device__ inline float exp2_fast(float x) { return __builtin_amdgcn_exp2f(x); }

__device__ inline float gelu_f(float x) {
  float u = 0.7978845608028654f * (x + 0.044715f * x * x * x);
  float e = __expf(2.f * u);           // tanh(u) = 1 - 2/(e+1), safe at +-inf
  return x * (1.f - 1.f / (e + 1.f));  // == 0.5x(1+tanh(u))
}

// async global->LDS DMA, 16B per lane. LDS dest is wave-uniform base + lane*16.
typedef const __attribute__((address_space(1))) unsigned int* gas_u32;
typedef __attribute__((address_space(3))) unsigned int* las_u32;
__device__ inline void async_copy16(const void* g, void* l) {
  __builtin_amdgcn_global_load_lds((gas_u32)g, (las_u32)l, 16, 0, 0);
}

// ---------------- f32 -> bf16 convert, x4 vectorized ----------------
__global__ __launch_bounds__(256) void cvt4_kernel(
    const float* __restrict__ in, bf16_t* __restrict__ out, int n4) {
  int i = blockIdx.x * 256 + threadIdx.x;
  if (i >= n4) return;
  float4 v = ((const float4*)in)[i];
  bf16x4 o = {f2b(v.x), f2b(v.y), f2b(v.z), f2b(v.w)};
  ((bf16x4*)out)[i] = o;
}

// ---------------- tiled transpose+convert: out[N x K](bf16) = in[K x N](f32)^T ----------------
__global__ __launch_bounds__(256) void transpose_cvt_kernel(
    const float* __restrict__ in, bf16_t* __restrict__ out, int K, int N) {
  __shared__ float t[32][33];
  const int k0 = blockIdx.y * 32, n0 = blockIdx.x * 32;
  const int r = threadIdx.x >> 3, c4 = (threadIdx.x & 7) * 4;
  float4 v = *(const float4*)&in[(size_t)(k0 + r) * N + n0 + c4];
  t[r][c4 + 0] = v.x; t[r][c4 + 1] = v.y; t[r][c4 + 2] = v.z; t[r][c4 + 3] = v.w;
  __syncthreads();
  bf16x4 o = {f2b(t[c4 + 0][r]), f2b(t[c4 + 1][r]), f2b(t[c4 + 2][r]), f2b(t[c4 + 3][r])};
  *(bf16x4*)&out[(size_t)(n0 + r) * K + k0 + c4] = o;
}

// ---- 4x batched 768x768 transpose+convert (one launch, blockIdx.z selects matrix) ----
__global__ __launch_bounds__(256) void transpose_cvt4x_kernel(
    const float* __restrict__ s0, const float* __restrict__ s1,
    const float* __restrict__ s2, const float* __restrict__ s3,
    bf16_t* __restrict__ d0, bf16_t* __restrict__ d1,
    bf16_t* __restrict__ d2, bf16_t* __restrict__ d3) {
  __shared__ float t[32][33];
  const int z = blockIdx.z;
  const float* in = (z == 0) ? s0 : (z == 1) ? s1 : (z == 2) ? s2 : s3;
  bf16_t* out = (z == 0) ? d0 : (z == 1) ? d1 : (z == 2) ? d2 : d3;
  const int k0 = blockIdx.y * 32, n0 = blockIdx.x * 32;
  const int r = threadIdx.x >> 3, c4 = (threadIdx.x & 7) * 4;
  float4 v = *(const float4*)&in[(size_t)(k0 + r) * 768 + n0 + c4];
  t[r][c4 + 0] = v.x; t[r][c4 + 1] = v.y; t[r][c4 + 2] = v.z; t[r][c4 + 3] = v.w;
  __syncthreads();
  bf16x4 o = {f2b(t[c4 + 0][r]), f2b(t[c4 + 1][r]), f2b(t[c4 + 2][r]), f2b(t[c4 + 3][r])};
  *(bf16x4*)&out[(size_t)(n0 + r) * 768 + k0 + c4] = o;
}

// ---------------- GEMM: C[M,N] = A[M,K] @ Bt[N,K]^T + bias, epilogue ----------------
// EPI 0: bias only; EPI 2: gelu(val+bias); EPI 3: fused QKV (seg epilogue + rel bias on q,v)
// Staging via global_load_lds (m97 structure): 2 barriers/K-step, DMA direct to LDS.
template <int EPI, int BN>
__global__ __launch_bounds__(256) void gemm_bt(
    const bf16_t* __restrict__ A, const bf16_t* __restrict__ Bt,
    const float* __restrict__ bias, bf16_t* __restrict__ C,
    int M, int N, int K,
    bf16_t* __restrict__ q_out, bf16_t* __restrict__ k_out, bf16_t* __restrict__ v_out,
    const float* __restrict__ bqp, const float* __restrict__ bkp, const float* __restrict__ bvp) {
  __shared__ __align__(16) bf16_t ldsA[128 * 32];
  __shared__ __align__(16) bf16_t ldsB[BN * 32];
  const int tid = threadIdx.x;
  const int lane = tid & 63, wave = tid >> 6;
  const int quad = lane >> 4, lq = lane & 15;
  const int bm = blockIdx.x * 128, bn = blockIdx.y * BN;
  const int wm = (wave & 1) * 64;
  const int wn = (wave >> 1) * (BN / 2);
  constexpr int JT = BN / 32;  // col-tiles per wave

  f32x4 acc[4][JT] = {};

  const int srow = tid >> 2;       // 0..63
  const int scb = (tid & 3) * 16;  // byte offset within 64B k-row

#pragma unroll 1
  for (int k0 = 0; k0 < K; k0 += 32) {
    __syncthreads();  // prior iteration's ds_reads complete before DMA overwrite
    {
      const char* a0 = (const char*)A + ((size_t)(bm + srow) * K + k0) * 2 + scb;
      const char* a1 = (const char*)A + ((size_t)(bm + 64 + srow) * K + k0) * 2 + scb;
      async_copy16(a0, (char*)ldsA + wave * 1024);
      async_copy16(a1, (char*)ldsA + 4096 + wave * 1024);
#pragma unroll
      for (int bb = 0; bb < BN / 64; ++bb) {
        const char* bsrc = (const char*)Bt + ((size_t)(bn + bb * 64 + srow) * K + k0) * 2 + scb;
        async_copy16(bsrc, (char*)ldsB + bb * 4096 + wave * 1024);
      }
    }
    __syncthreads();  // compiler drains vmcnt(0) before barrier -> LDS valid
    bf16x8 af[4], bfr[JT];
#pragma unroll
    for (int i = 0; i < 4; ++i)
      af[i] = *(const bf16x8*)&ldsA[(wm + i * 16 + lq) * 32 + quad * 8];
#pragma unroll
    for (int j = 0; j < JT; ++j)
      bfr[j] = *(const bf16x8*)&ldsB[(wn + j * 16 + lq) * 32 + quad * 8];
#pragma unroll
    for (int i = 0; i < 4; ++i)
#pragma unroll
      for (int j = 0; j < JT; ++j)
        acc[i][j] = __builtin_amdgcn_mfma_f32_16x16x32_bf16(af[i], bfr[j], acc[i][j], 0, 0, 0);
  }

#pragma unroll
  for (int i = 0; i < 4; ++i) {
#pragma unroll
    for (int j = 0; j < JT; ++j) {
      const int n = bn + wn + j * 16 + lq;
      if (EPI == 3) {
        const int seg = n / 768;          // uniform within the 16-col group
        const int nc = n - seg * 768;
        bf16_t* op = (seg == 0) ? q_out : (seg == 1) ? k_out : v_out;
        const float* bp = (seg == 0) ? bqp : (seg == 1) ? bkp : bvp;
        const float bv_ = bp[nc];
#pragma unroll
        for (int r = 0; r < 4; ++r) {
          const int m = bm + wm + i * 16 + quad * 4 + r;
          float v = acc[i][j][r] + bv_;
          if (seg != 1) {
            float rel = (float)(nc - (m & 2047));
            v += fminf(fmaxf(rel, -3.f), 3.f);
          }
          op[(size_t)m * 768 + nc] = f2b(v);
        }
      } else {
        const float bv_ = bias[n];
#pragma unroll
        for (int r = 0; r < 4; ++r) {
          const int m = bm + wm + i * 16 + quad * 4 + r;
          float v = acc[i][j][r] + bv_;
          if (EPI == 2) v = gelu_f(v);
          C[(size_t)m * N + n] = f2b(v);
        }
      }
    }
  }
}

// ---------------- attention: 64 q-rows/block, 128-wide K-tiles ----------------
// Softmax in exp2 domain (log2e folded into scale); pass A uses a branchless
// single-transcendental online update.
__global__ __launch_bounds__(256) void attn_kernel(
    const bf16_t* __restrict__ Q, const bf16_t* __restrict__ Km,
    const bf16_t* __restrict__ V, const float* __restrict__ mask,
    float* __restrict__ attn, bf16_t* __restrict__ ctx) {
  __shared__ __align__(16) bf16_t ldsK[128 * 68];     // [kpos][d], stride 68
  __shared__ __align__(16) bf16_t ldsVT[64 * 132];    // [d][kpos], stride 132
  __shared__ __align__(16) bf16_t ldsP[4][16 * 132];  // per-wave P, stride 132
  const int tid = threadIdx.x;
  const int lane = tid & 63, wave = tid >> 6;
  const int quad = lane >> 4, lq = lane & 15;
  const int qblk = blockIdx.x & 31, bh = blockIdx.x >> 5;
  const int b = bh / HH;
  const int qbase = qblk * 64 + wave * 16;

  const bf16_t* qh = Q + (size_t)bh * (SS * HDIM);
  const bf16_t* kh = Km + (size_t)bh * (SS * HDIM);
  const bf16_t* vh = V + (size_t)bh * (SS * HDIM);
  const float* mrow = mask + (size_t)b * SS * SS;

  // 1/sqrt(768) * log2(e): softmax computed base-2 (mask multiplies linearly,
  // so folding the base change into the scale commutes with it)
  const float scale2 = 0.03608439182435161f * 1.4426950408889634f;

  bf16x8 aq[2];
#pragma unroll
  for (int hf = 0; hf < 2; ++hf)
    aq[hf] = *(const bf16x8*)(qh + (size_t)(qbase + lq) * HDIM + hf * 32 + quad * 8);

  const int srow = tid >> 3;       // 0..31 per round
  const int sc8 = (tid & 7) * 8;   // element offset within 64-wide row

  float mrun[4], lrun[4];
#pragma unroll
  for (int r = 0; r < 4; ++r) { mrun[r] = -1e30f; lrun[r] = 0.f; }

  // -------- pass A: exact online (max, sumexp2) --------
#pragma unroll 1
  for (int kt = 0; kt < 16; ++kt) {
    const int kbase = kt * 128;
    bf16x8 kvv[4];
#pragma unroll
    for (int rd = 0; rd < 4; ++rd)
      kvv[rd] = *(const bf16x8*)(kh + (size_t)(kbase + rd * 32 + srow) * HDIM + sc8);
    __syncthreads();
#pragma unroll
    for (int rd = 0; rd < 4; ++rd)
      *(bf16x8*)&ldsK[(rd * 32 + srow) * 68 + sc8] = kvv[rd];
    __syncthreads();
#pragma unroll
    for (int ct = 0; ct < 8; ++ct) {
      bf16x8 bk0 = *(const bf16x8*)&ldsK[(ct * 16 + lq) * 68 + quad * 8];
      bf16x8 bk1 = *(const bf16x8*)&ldsK[(ct * 16 + lq) * 68 + 32 + quad * 8];
      f32x4 s4 = {};
      s4 = __builtin_amdgcn_mfma_f32_16x16x32_bf16(aq[0], bk0, s4, 0, 0, 0);
      s4 = __builtin_amdgcn_mfma_f32_16x16x32_bf16(aq[1], bk1, s4, 0, 0, 0);
      const int col = kbase + ct * 16 + lq;
#pragma unroll
      for (int r = 0; r < 4; ++r) {
        const int row = qbase + quad * 4 + r;
        float sv = s4[r] * scale2 * mrow[(size_t)row * SS + col];
        float d = sv - mrun[r];
        float e = exp2_fast(-fabsf(d));   // single transcendental per element
        bool gt = d > 0.f;
        lrun[r] = gt ? (lrun[r] * e + 1.f) : (lrun[r] + e);
        mrun[r] = gt ? sv : mrun[r];
      }
    }
  }
#pragma unroll
  for (int xm = 1; xm <= 8; xm <<= 1) {
#pragma unroll
    for (int r = 0; r < 4; ++r) {
      float mo = __shfl_xor(mrun[r], xm);
      float lo = __shfl_xor(lrun[r], xm);
      float mm = fmaxf(mrun[r], mo);
      lrun[r] = lrun[r] * exp2_fast(mrun[r] - mm) + lo * exp2_fast(mo - mm);
      mrun[r] = mm;
    }
  }
  float linv[4];
#pragma unroll
  for (int r = 0; r < 4; ++r) linv[r] = 1.f / lrun[r];

  // -------- pass B: P = exp2(s-m)/l, write attn (f32), O += P@V --------
  f32x4 oacc[4] = {};
  float* attnrow = attn + (size_t)bh * SS * SS;

#pragma unroll 1
  for (int kt = 0; kt < 16; ++kt) {
    const int kbase = kt * 128;
    bf16x8 kvv[4], vvv[4];
#pragma unroll
    for (int rd = 0; rd < 4; ++rd) {
      kvv[rd] = *(const bf16x8*)(kh + (size_t)(kbase + rd * 32 + srow) * HDIM + sc8);
      vvv[rd] = *(const bf16x8*)(vh + (size_t)(kbase + rd * 32 + srow) * HDIM + sc8);
    }
    __syncthreads();
#pragma unroll
    for (int rd = 0; rd < 4; ++rd) {
      const int row = rd * 32 + srow;
      *(bf16x8*)&ldsK[row * 68 + sc8] = kvv[rd];
#pragma unroll
      for (int j = 0; j < 8; ++j)
        ldsVT[(sc8 + j) * 132 + row] = vvv[rd][j];
    }
    __syncthreads();
#pragma unroll
    for (int ct = 0; ct < 8; ++ct) {
      bf16x8 bk0 = *(const bf16x8*)&ldsK[(ct * 16 + lq) * 68 + quad * 8];
      bf16x8 bk1 = *(const bf16x8*)&ldsK[(ct * 16 + lq) * 68 + 32 + quad * 8];
      f32x4 s4 = {};
      s4 = __builtin_amdgcn_mfma_f32_16x16x32_bf16(aq[0], bk0, s4, 0, 0, 0);
      s4 = __builtin_amdgcn_mfma_f32_16x16x32_bf16(aq[1], bk1, s4, 0, 0, 0);
      const int col = kbase + ct * 16 + lq;
#pragma unroll
      for (int r = 0; r < 4; ++r) {
        const int row = qbase + quad * 4 + r;
        float sv = s4[r] * scale2 * mrow[(size_t)row * SS + col];
        float p = exp2_fast(sv - mrun[r]) * linv[r];
        ldsP[wave][(quad * 4 + r) * 132 + ct * 16 + lq] = f2b(p);
      }
    }
    asm volatile("s_waitcnt lgkmcnt(0)" ::: "memory");
    // coalesced f32 attn store from wave-private P tile
#pragma unroll
    for (int rnd = 0; rnd < 4; ++rnd) {
      const int c = rnd * 64 + lane;
      const int prow = c >> 4, pc = c & 15;
      bf16x8 pv = *(const bf16x8*)&ldsP[wave][prow * 132 + pc * 8];
      float4 f0 = {b2f(pv[0]), b2f(pv[1]), b2f(pv[2]), b2f(pv[3])};
      float4 f1 = {b2f(pv[4]), b2f(pv[5]), b2f(pv[6]), b2f(pv[7])};
      float* dst = attnrow + (size_t)(qbase + prow) * SS + kbase + pc * 8;
      *(float4*)dst = f0;
      *(float4*)(dst + 4) = f1;
    }
    // O += P @ V
#pragma unroll
    for (int kc = 0; kc < 4; ++kc) {
      bf16x8 pf = *(const bf16x8*)&ldsP[wave][lq * 132 + kc * 32 + quad * 8];
#pragma unroll
      for (int dt = 0; dt < 4; ++dt) {
        bf16x8 vf = *(const bf16x8*)&ldsVT[(dt * 16 + lq) * 132 + kc * 32 + quad * 8];
        oacc[dt] = __builtin_amdgcn_mfma_f32_16x16x32_bf16(pf, vf, oacc[dt], 0, 0, 0);
      }
    }
  }

  bf16_t* ch = ctx + (size_t)bh * (SS * HDIM);
#pragma unroll
  for (int dt = 0; dt < 4; ++dt)
#pragma unroll
    for (int r = 0; r < 4; ++r)
      ch[(size_t)(qbase + quad * 4 + r) * HDIM + dt * 16 + lq] = f2b(oacc[dt][r]);
}

// ---------------- residual + LayerNorm over 768 ----------------
template <typename TR, typename TO>
__global__ __launch_bounds__(256) void ln_res_kernel(
    const bf16_t* __restrict__ a, const TR* __restrict__ res,
    const float* __restrict__ sc, const float* __restrict__ bi,
    TO* __restrict__ out) {
  __shared__ float red[8];
  const int row = blockIdx.x, tid = threadIdx.x;
  const size_t base = (size_t)row * DD;
  float v0 = b2f(a[base + tid]) + (float)res[base + tid];
  float v1 = b2f(a[base + 256 + tid]) + (float)res[base + 256 + tid];
  float v2 = b2f(a[base + 512 + tid]) + (float)res[base + 512 + tid];
  float s = v0 + v1 + v2;
#pragma unroll
  for (int o = 32; o; o >>= 1) s += __shfl_down(s, o, 64);
  if ((tid & 63) == 0) red[tid >> 6] = s;
  __syncthreads();
  const float mean = (red[0] + red[1] + red[2] + red[3]) * (1.f / 768.f);
  const float d0 = v0 - mean, d1 = v1 - mean, d2 = v2 - mean;
  float q = d0 * d0 + d1 * d1 + d2 * d2;
#pragma unroll
  for (int o = 32; o; o >>= 1) q += __shfl_down(q, o, 64);
  if ((tid & 63) == 0) red[4 + (tid >> 6)] = q;
  __syncthreads();
  const float var = (red[4] + red[5] + red[6] + red[7]) * (1.f / 768.f);
  const float rs = rsqrtf(var + 1e-6f);
  out[base + tid]       = (TO)(d0 * rs * sc[tid]       + bi[tid]);
  out[base + 256 + tid] = (TO)(d1 * rs * sc[256 + tid] + bi[256 + tid]);
  out[base + 512 + tid] = (TO)(d2 * rs * sc[512 + tid] + bi[512 + tid]);
}

extern "C" void kernel_launch(void* const* d_in, const int* in_sizes, int n_in,
                              void* d_out, int out_size, void* d_ws, size_t ws_size,
                              hipStream_t stream) {
  (void)in_sizes; (void)n_in; (void)out_size; (void)ws_size;
  const float* x    = (const float*)d_in[0];
  const float* mask = (const float*)d_in[1];
  const float* Wq = (const float*)d_in[2];
  const float* bq = (const float*)d_in[3];
  const float* Wk = (const float*)d_in[4];
  const float* bk = (const float*)d_in[5];
  const float* Wv = (const float*)d_in[6];
  const float* bv = (const float*)d_in[7];
  const float* Wo = (const float*)d_in[8];
  const float* bo = (const float*)d_in[9];
  const float* W1 = (const float*)d_in[10];
  const float* b1 = (const float*)d_in[11];
  const float* W2 = (const float*)d_in[12];
  const float* b2 = (const float*)d_in[13];
  const float* ln1s = (const float*)d_in[14];
  const float* ln1b = (const float*)d_in[15];
  const float* ln2s = (const float*)d_in[16];
  const float* ln2b = (const float*)d_in[17];
  float* out = (float*)d_out;
  float* attn_out = out + 3145728;  // x2 is 2*2048*768

  // bf16 workspace layout (element offsets); hb overlays kb/vb/ctx (dead by then)
  bf16_t* ws  = (bf16_t*)d_ws;
  bf16_t* wqT = ws;                     // 589824  (wq/wk/wv contiguous = fused 2304x768)
  bf16_t* wkT = wqT + 589824;
  bf16_t* wvT = wkT + 589824;
  bf16_t* woT = wvT + 589824;
  bf16_t* w1T = woT + 589824;           // 2359296
  bf16_t* w2T = w1T + 2359296;          // 2359296
  bf16_t* xb  = w2T + 2359296;          // 3145728
  bf16_t* x1  = xb  + 3145728;          // 3145728
  bf16_t* qb  = x1  + 3145728;          // 3145728
  bf16_t* kb  = qb  + 3145728;          // 3145728
  bf16_t* vb  = kb  + 3145728;          // 3145728
  bf16_t* ctx = vb  + 3145728;          // 3145728
  bf16_t* hb  = kb;                     // FFN hidden overlays kb/vb/ctx + tail
  bf16_t* att = qb;                     // reuse (q dead after attention)
  bf16_t* yb  = qb;                     // reuse (att dead after ln1)

  // single launch for all four 768x768 weight transposes (saves 3 dispatch gaps)
  transpose_cvt4x_kernel<<<dim3(24, 24, 4), 256, 0, stream>>>(Wq, Wk, Wv, Wo,
                                                              wqT, wkT, wvT, woT);
  transpose_cvt_kernel<<<dim3(96, 24), 256, 0, stream>>>(W1, w1T, 768, 3072);
  transpose_cvt_kernel<<<dim3(24, 96), 256, 0, stream>>>(W2, w2T, 3072, 768);
  cvt4_kernel<<<3072, 256, 0, stream>>>(x, xb, 786432);

  dim3 blk(256);
  gemm_bt<3, 128><<<dim3(32, 18), blk, 0, stream>>>(xb, wqT, nullptr, nullptr, MROWS, 2304, 768,
                                                    qb, kb, vb, bq, bk, bv);
  attn_kernel<<<768, blk, 0, stream>>>(qb, kb, vb, mask, attn_out, ctx);
  gemm_bt<0, 64><<<dim3(32, 12), blk, 0, stream>>>(ctx, woT, bo, att, MROWS, 768, 768,
                                                   nullptr, nullptr, nullptr, nullptr, nullptr, nullptr);
  ln_res_kernel<float, bf16_t><<<MROWS, blk, 0, stream>>>(att, x, ln1s, ln1b, x1);
  gemm_bt<2, 128><<<dim3(32, 24), blk, 0, stream>>>(x1, w1T, b1, hb, MROWS, FFD, 768,
                                                    nullptr, nullptr, nullptr, nullptr, nullptr, nullptr);
  gemm_bt<0, 64><<<dim3(32, 12), blk, 0, stream>>>(hb, w2T, b2, yb, MROWS, 768, FFD,
                                                   nullptr, nullptr, nullptr, nullptr, nullptr, nullptr);
  ln_res_kernel<bf16_t, float><<<MROWS, blk, 0, stream>>>(yb, x1, ln2s, ln2b, out);
}

// Round 5
// 764.106 us; speedup vs baseline: 1.1010x; 1.1010x over previous
//
#include <hip/hip_runtime.h>
#include <stdint.h>

#define SS 2048
#define DD 768
#define HH 12
#define HDIM 64
#define FFD 3072
#define MROWS 4096  // B*S

typedef __bf16 bf16_t;
using bf16x4 = __attribute__((ext_vector_type(4))) __bf16;
using bf16x8 = __attribute__((ext_vector_type(8))) __bf16;
using f32x4  = __attribute__((ext_vector_type(4))) float;

__device__ inline float b2f(bf16_t v) { return (float)v; }
__device__ inline bf16_t f2b(float v) { return (bf16_t)v; }

// native v_exp_f32 (2^x). NOTE: __exp2f is NOT a HIP device intrinsic (glibc
// macro collision at compile time) — must use the amdgcn builtin.
__device__ inline float exp2_fast(float x) { return __builtin_amdgcn_exp2f(x); }

__device__ inline float gelu_f(float x) {
  float u = 0.7978845608028654f * (x + 0.044715f * x * x * x);
  float e = __expf(2.f * u);           // tanh(u) = 1 - 2/(e+1), safe at +-inf
  return x * (1.f - 1.f / (e + 1.f));  // == 0.5x(1+tanh(u))
}

// async global->LDS DMA, 16B per lane. LDS dest is wave-uniform base + lane*16.
typedef const __attribute__((address_space(1))) unsigned int* gas_u32;
typedef __attribute__((address_space(3))) unsigned int* las_u32;
__device__ inline void async_copy16(const void* g, void* l) {
  __builtin_amdgcn_global_load_lds((gas_u32)g, (las_u32)l, 16, 0, 0);
}

// ---------------- f32 -> bf16 convert, x4 vectorized ----------------
__global__ __launch_bounds__(256) void cvt4_kernel(
    const float* __restrict__ in, bf16_t* __restrict__ out, int n4) {
  int i = blockIdx.x * 256 + threadIdx.x;
  if (i >= n4) return;
  float4 v = ((const float4*)in)[i];
  bf16x4 o = {f2b(v.x), f2b(v.y), f2b(v.z), f2b(v.w)};
  ((bf16x4*)out)[i] = o;
}

// ---------------- tiled transpose+convert: out[N x K](bf16) = in[K x N](f32)^T ----------------
__global__ __launch_bounds__(256) void transpose_cvt_kernel(
    const float* __restrict__ in, bf16_t* __restrict__ out, int K, int N) {
  __shared__ float t[32][33];
  const int k0 = blockIdx.y * 32, n0 = blockIdx.x * 32;
  const int r = threadIdx.x >> 3, c4 = (threadIdx.x & 7) * 4;
  float4 v = *(const float4*)&in[(size_t)(k0 + r) * N + n0 + c4];
  t[r][c4 + 0] = v.x; t[r][c4 + 1] = v.y; t[r][c4 + 2] = v.z; t[r][c4 + 3] = v.w;
  __syncthreads();
  bf16x4 o = {f2b(t[c4 + 0][r]), f2b(t[c4 + 1][r]), f2b(t[c4 + 2][r]), f2b(t[c4 + 3][r])};
  *(bf16x4*)&out[(size_t)(n0 + r) * K + k0 + c4] = o;
}

// ---- 4x batched 768x768 transpose+convert (one launch, blockIdx.z selects matrix) ----
__global__ __launch_bounds__(256) void transpose_cvt4x_kernel(
    const float* __restrict__ s0, const float* __restrict__ s1,
    const float* __restrict__ s2, const float* __restrict__ s3,
    bf16_t* __restrict__ d0, bf16_t* __restrict__ d1,
    bf16_t* __restrict__ d2, bf16_t* __restrict__ d3) {
  __shared__ float t[32][33];
  const int z = blockIdx.z;
  const float* in = (z == 0) ? s0 : (z == 1) ? s1 : (z == 2) ? s2 : s3;
  bf16_t* out = (z == 0) ? d0 : (z == 1) ? d1 : (z == 2) ? d2 : d3;
  const int k0 = blockIdx.y * 32, n0 = blockIdx.x * 32;
  const int r = threadIdx.x >> 3, c4 = (threadIdx.x & 7) * 4;
  float4 v = *(const float4*)&in[(size_t)(k0 + r) * 768 + n0 + c4];
  t[r][c4 + 0] = v.x; t[r][c4 + 1] = v.y; t[r][c4 + 2] = v.z; t[r][c4 + 3] = v.w;
  __syncthreads();
  bf16x4 o = {f2b(t[c4 + 0][r]), f2b(t[c4 + 1][r]), f2b(t[c4 + 2][r]), f2b(t[c4 + 3][r])};
  *(bf16x4*)&out[(size_t)(n0 + r) * 768 + k0 + c4] = o;
}

// ---------------- GEMM: C[M,N] = A[M,K] @ Bt[N,K]^T + bias, epilogue ----------------
// EPI 0: bias only; EPI 2: gelu(val+bias); EPI 3: fused QKV (seg epilogue + rel bias on q,v)
// Staging via global_load_lds (m97 structure): 2 barriers/K-step, DMA direct to LDS.
template <int EPI, int BN>
__global__ __launch_bounds__(256) void gemm_bt(
    const bf16_t* __restrict__ A, const bf16_t* __restrict__ Bt,
    const float* __restrict__ bias, bf16_t* __restrict__ C,
    int M, int N, int K,
    bf16_t* __restrict__ q_out, bf16_t* __restrict__ k_out, bf16_t* __restrict__ v_out,
    const float* __restrict__ bqp, const float* __restrict__ bkp, const float* __restrict__ bvp) {
  __shared__ __align__(16) bf16_t ldsA[128 * 32];
  __shared__ __align__(16) bf16_t ldsB[BN * 32];
  const int tid = threadIdx.x;
  const int lane = tid & 63, wave = tid >> 6;
  const int quad = lane >> 4, lq = lane & 15;
  const int bm = blockIdx.x * 128, bn = blockIdx.y * BN;
  const int wm = (wave & 1) * 64;
  const int wn = (wave >> 1) * (BN / 2);
  constexpr int JT = BN / 32;  // col-tiles per wave

  f32x4 acc[4][JT] = {};

  const int srow = tid >> 2;       // 0..63
  const int scb = (tid & 3) * 16;  // byte offset within 64B k-row

#pragma unroll 1
  for (int k0 = 0; k0 < K; k0 += 32) {
    __syncthreads();  // prior iteration's ds_reads complete before DMA overwrite
    {
      const char* a0 = (const char*)A + ((size_t)(bm + srow) * K + k0) * 2 + scb;
      const char* a1 = (const char*)A + ((size_t)(bm + 64 + srow) * K + k0) * 2 + scb;
      async_copy16(a0, (char*)ldsA + wave * 1024);
      async_copy16(a1, (char*)ldsA + 4096 + wave * 1024);
#pragma unroll
      for (int bb = 0; bb < BN / 64; ++bb) {
        const char* bsrc = (const char*)Bt + ((size_t)(bn + bb * 64 + srow) * K + k0) * 2 + scb;
        async_copy16(bsrc, (char*)ldsB + bb * 4096 + wave * 1024);
      }
    }
    __syncthreads();  // compiler drains vmcnt(0) before barrier -> LDS valid
    bf16x8 af[4], bfr[JT];
#pragma unroll
    for (int i = 0; i < 4; ++i)
      af[i] = *(const bf16x8*)&ldsA[(wm + i * 16 + lq) * 32 + quad * 8];
#pragma unroll
    for (int j = 0; j < JT; ++j)
      bfr[j] = *(const bf16x8*)&ldsB[(wn + j * 16 + lq) * 32 + quad * 8];
#pragma unroll
    for (int i = 0; i < 4; ++i)
#pragma unroll
      for (int j = 0; j < JT; ++j)
        acc[i][j] = __builtin_amdgcn_mfma_f32_16x16x32_bf16(af[i], bfr[j], acc[i][j], 0, 0, 0);
  }

#pragma unroll
  for (int i = 0; i < 4; ++i) {
#pragma unroll
    for (int j = 0; j < JT; ++j) {
      const int n = bn + wn + j * 16 + lq;
      if (EPI == 3) {
        const int seg = n / 768;          // uniform within the 16-col group
        const int nc = n - seg * 768;
        bf16_t* op = (seg == 0) ? q_out : (seg == 1) ? k_out : v_out;
        const float* bp = (seg == 0) ? bqp : (seg == 1) ? bkp : bvp;
        const float bv_ = bp[nc];
#pragma unroll
        for (int r = 0; r < 4; ++r) {
          const int m = bm + wm + i * 16 + quad * 4 + r;
          float v = acc[i][j][r] + bv_;
          if (seg != 1) {
            float rel = (float)(nc - (m & 2047));
            v += fminf(fmaxf(rel, -3.f), 3.f);
          }
          op[(size_t)m * 768 + nc] = f2b(v);
        }
      } else {
        const float bv_ = bias[n];
#pragma unroll
        for (int r = 0; r < 4; ++r) {
          const int m = bm + wm + i * 16 + quad * 4 + r;
          float v = acc[i][j][r] + bv_;
          if (EPI == 2) v = gelu_f(v);
          C[(size_t)m * N + n] = f2b(v);
        }
      }
    }
  }
}

// ---------------- attention: 64 q-rows/block, 128-wide K-tiles ----------------
// (1) per-tile hoisted mask loads; (2) software prefetch of next K/V tile;
// (3) ldsVT XOR swizzle ((d>>3)^d)&7: write 2-way free AND PV-read bases
//     spread over all 8 16B bank-groups (round-3's (d>>3)-only XOR collapsed
//     the read to 4 groups = ~16-way conflict; d-bits alone are bank-invisible
//     at stride 256B so the XOR must mix BOTH d>>3 (write spread) and d&7
//     (read spread)).
__global__ __launch_bounds__(256) void attn_kernel(
    const bf16_t* __restrict__ Q, const bf16_t* __restrict__ Km,
    const bf16_t* __restrict__ V, const float* __restrict__ mask,
    float* __restrict__ attn, bf16_t* __restrict__ ctx) {
  __shared__ __align__(16) bf16_t ldsK[128 * 68];     // [kpos][d], stride 68
  __shared__ __align__(16) bf16_t ldsVT[64 * 128];    // [d][kpos], XOR-swizzled
  __shared__ __align__(16) bf16_t ldsP[4][16 * 132];  // per-wave P, stride 132
  const int tid = threadIdx.x;
  const int lane = tid & 63, wave = tid >> 6;
  const int quad = lane >> 4, lq = lane & 15;
  const int qblk = blockIdx.x & 31, bh = blockIdx.x >> 5;
  const int b = bh / HH;
  const int qbase = qblk * 64 + wave * 16;

  const bf16_t* qh = Q + (size_t)bh * (SS * HDIM);
  const bf16_t* kh = Km + (size_t)bh * (SS * HDIM);
  const bf16_t* vh = V + (size_t)bh * (SS * HDIM);
  const float* mrow = mask + (size_t)b * SS * SS;

  // 1/sqrt(768) * log2(e): softmax computed base-2 (mask multiplies linearly,
  // so folding the base change into the scale commutes with it)
  const float scale2 = 0.03608439182435161f * 1.4426950408889634f;

  bf16x8 aq[2];
#pragma unroll
  for (int hf = 0; hf < 2; ++hf)
    aq[hf] = *(const bf16x8*)(qh + (size_t)(qbase + lq) * HDIM + hf * 32 + quad * 8);

  const int srow = tid >> 3;       // 0..31 per round
  const int sc8 = (tid & 7) * 8;   // element offset within 64-wide row

  float mrun[4], lrun[4];
#pragma unroll
  for (int r = 0; r < 4; ++r) { mrun[r] = -1e30f; lrun[r] = 0.f; }

  // -------- pass A: exact online (max, sumexp2) --------
  bf16x8 kvv[4];
#pragma unroll
  for (int rd = 0; rd < 4; ++rd)
    kvv[rd] = *(const bf16x8*)(kh + (size_t)(rd * 32 + srow) * HDIM + sc8);

#pragma unroll 1
  for (int kt = 0; kt < 16; ++kt) {
    const int kbase = kt * 128;
    __syncthreads();
#pragma unroll
    for (int rd = 0; rd < 4; ++rd)
      *(bf16x8*)&ldsK[(rd * 32 + srow) * 68 + sc8] = kvv[rd];
    __syncthreads();
    // prefetch next K tile under this tile's compute
    if (kt < 15) {
#pragma unroll
      for (int rd = 0; rd < 4; ++rd)
        kvv[rd] = *(const bf16x8*)(kh + (size_t)(kbase + 128 + rd * 32 + srow) * HDIM + sc8);
    }
    // hoisted mask loads: 32 independent dwords, batch-issued once per tile
    float mk[8][4];
#pragma unroll
    for (int ct = 0; ct < 8; ++ct)
#pragma unroll
      for (int r = 0; r < 4; ++r)
        mk[ct][r] = mrow[(size_t)(qbase + quad * 4 + r) * SS + kbase + ct * 16 + lq];
#pragma unroll
    for (int ct = 0; ct < 8; ++ct) {
      bf16x8 bk0 = *(const bf16x8*)&ldsK[(ct * 16 + lq) * 68 + quad * 8];
      bf16x8 bk1 = *(const bf16x8*)&ldsK[(ct * 16 + lq) * 68 + 32 + quad * 8];
      f32x4 s4 = {};
      s4 = __builtin_amdgcn_mfma_f32_16x16x32_bf16(aq[0], bk0, s4, 0, 0, 0);
      s4 = __builtin_amdgcn_mfma_f32_16x16x32_bf16(aq[1], bk1, s4, 0, 0, 0);
#pragma unroll
      for (int r = 0; r < 4; ++r) {
        float sv = s4[r] * scale2 * mk[ct][r];
        float d = sv - mrun[r];
        float e = exp2_fast(-fabsf(d));   // single transcendental per element
        bool gt = d > 0.f;
        lrun[r] = gt ? (lrun[r] * e + 1.f) : (lrun[r] + e);
        mrun[r] = gt ? sv : mrun[r];
      }
    }
  }
#pragma unroll
  for (int xm = 1; xm <= 8; xm <<= 1) {
#pragma unroll
    for (int r = 0; r < 4; ++r) {
      float mo = __shfl_xor(mrun[r], xm);
      float lo = __shfl_xor(lrun[r], xm);
      float mm = fmaxf(mrun[r], mo);
      lrun[r] = lrun[r] * exp2_fast(mrun[r] - mm) + lo * exp2_fast(mo - mm);
      mrun[r] = mm;
    }
  }
  float linv[4];
#pragma unroll
  for (int r = 0; r < 4; ++r) linv[r] = 1.f / lrun[r];

  // -------- pass B: P = exp2(s-m)/l, write attn (f32), O += P@V --------
  f32x4 oacc[4] = {};
  float* attnrow = attn + (size_t)bh * SS * SS;

  bf16x8 vvv[4];
#pragma unroll
  for (int rd = 0; rd < 4; ++rd) {
    kvv[rd] = *(const bf16x8*)(kh + (size_t)(rd * 32 + srow) * HDIM + sc8);
    vvv[rd] = *(const bf16x8*)(vh + (size_t)(rd * 32 + srow) * HDIM + sc8);
  }

#pragma unroll 1
  for (int kt = 0; kt < 16; ++kt) {
    const int kbase = kt * 128;
    __syncthreads();
#pragma unroll
    for (int rd = 0; rd < 4; ++rd) {
      const int row = rd * 32 + srow;
      *(bf16x8*)&ldsK[row * 68 + sc8] = kvv[rd];
      // V transpose write, XOR-swizzled with ((d>>3)^d)&7: per-instruction the
      // write spreads by tid&7 (2-way free); the PV read spreads by lq&7^lq>>3
      // (all 8 bank-groups covered).
#pragma unroll
      for (int j = 0; j < 8; ++j) {
        const int d = sc8 + j;
        const unsigned wbyte =
            (unsigned)(d * 256 + row * 2) ^ (unsigned)((((d >> 3) ^ d) & 7) << 4);
        *(bf16_t*)((char*)ldsVT + wbyte) = vvv[rd][j];
      }
    }
    __syncthreads();
    // prefetch next K/V tile under this tile's compute
    if (kt < 15) {
#pragma unroll
      for (int rd = 0; rd < 4; ++rd) {
        kvv[rd] = *(const bf16x8*)(kh + (size_t)(kbase + 128 + rd * 32 + srow) * HDIM + sc8);
        vvv[rd] = *(const bf16x8*)(vh + (size_t)(kbase + 128 + rd * 32 + srow) * HDIM + sc8);
      }
    }
    float mk[8][4];
#pragma unroll
    for (int ct = 0; ct < 8; ++ct)
#pragma unroll
      for (int r = 0; r < 4; ++r)
        mk[ct][r] = mrow[(size_t)(qbase + quad * 4 + r) * SS + kbase + ct * 16 + lq];
#pragma unroll
    for (int ct = 0; ct < 8; ++ct) {
      bf16x8 bk0 = *(const bf16x8*)&ldsK[(ct * 16 + lq) * 68 + quad * 8];
      bf16x8 bk1 = *(const bf16x8*)&ldsK[(ct * 16 + lq) * 68 + 32 + quad * 8];
      f32x4 s4 = {};
      s4 = __builtin_amdgcn_mfma_f32_16x16x32_bf16(aq[0], bk0, s4, 0, 0, 0);
      s4 = __builtin_amdgcn_mfma_f32_16x16x32_bf16(aq[1], bk1, s4, 0, 0, 0);
#pragma unroll
      for (int r = 0; r < 4; ++r) {
        float sv = s4[r] * scale2 * mk[ct][r];
        float p = exp2_fast(sv - mrun[r]) * linv[r];
        ldsP[wave][(quad * 4 + r) * 132 + ct * 16 + lq] = f2b(p);
      }
    }
    asm volatile("s_waitcnt lgkmcnt(0)" ::: "memory");
    // coalesced f32 attn store from wave-private P tile
#pragma unroll
    for (int rnd = 0; rnd < 4; ++rnd) {
      const int c = rnd * 64 + lane;
      const int prow = c >> 4, pc = c & 15;
      bf16x8 pv = *(const bf16x8*)&ldsP[wave][prow * 132 + pc * 8];
      float4 f0 = {b2f(pv[0]), b2f(pv[1]), b2f(pv[2]), b2f(pv[3])};
      float4 f1 = {b2f(pv[4]), b2f(pv[5]), b2f(pv[6]), b2f(pv[7])};
      float* dst = attnrow + (size_t)(qbase + prow) * SS + kbase + pc * 8;
      *(float4*)dst = f0;
      *(float4*)(dst + 4) = f1;
    }
    // O += P @ V
#pragma unroll
    for (int kc = 0; kc < 4; ++kc) {
      bf16x8 pf = *(const bf16x8*)&ldsP[wave][lq * 132 + kc * 32 + quad * 8];
#pragma unroll
      for (int dt = 0; dt < 4; ++dt) {
        const int vd = dt * 16 + lq;
        const unsigned vbyte = (unsigned)(vd * 256 + (kc * 32 + quad * 8) * 2) ^
                               (unsigned)((((vd >> 3) ^ vd) & 7) << 4);
        bf16x8 vf = *(const bf16x8*)((const char*)ldsVT + vbyte);
        oacc[dt] = __builtin_amdgcn_mfma_f32_16x16x32_bf16(pf, vf, oacc[dt], 0, 0, 0);
      }
    }
  }

  bf16_t* ch = ctx + (size_t)bh * (SS * HDIM);
#pragma unroll
  for (int dt = 0; dt < 4; ++dt)
#pragma unroll
    for (int r = 0; r < 4; ++r)
      ch[(size_t)(qbase + quad * 4 + r) * HDIM + dt * 16 + lq] = f2b(oacc[dt][r]);
}

// ---------------- residual + LayerNorm over 768 ----------------
template <typename TR, typename TO>
__global__ __launch_bounds__(256) void ln_res_kernel(
    const bf16_t* __restrict__ a, const TR* __restrict__ res,
    const float* __restrict__ sc, const float* __restrict__ bi,
    TO* __restrict__ out) {
  __shared__ float red[8];
  const int row = blockIdx.x, tid = threadIdx.x;
  const size_t base = (size_t)row * DD;
  float v0 = b2f(a[base + tid]) + (float)res[base + tid];
  float v1 = b2f(a[base + 256 + tid]) + (float)res[base + 256 + tid];
  float v2 = b2f(a[base + 512 + tid]) + (float)res[base + 512 + tid];
  float s = v0 + v1 + v2;
#pragma unroll
  for (int o = 32; o; o >>= 1) s += __shfl_down(s, o, 64);
  if ((tid & 63) == 0) red[tid >> 6] = s;
  __syncthreads();
  const float mean = (red[0] + red[1] + red[2] + red[3]) * (1.f / 768.f);
  const float d0 = v0 - mean, d1 = v1 - mean, d2 = v2 - mean;
  float q = d0 * d0 + d1 * d1 + d2 * d2;
#pragma unroll
  for (int o = 32; o; o >>= 1) q += __shfl_down(q, o, 64);
  if ((tid & 63) == 0) red[4 + (tid >> 6)] = q;
  __syncthreads();
  const float var = (red[4] + red[5] + red[6] + red[7]) * (1.f / 768.f);
  const float rs = rsqrtf(var + 1e-6f);
  out[base + tid]       = (TO)(d0 * rs * sc[tid]       + bi[tid]);
  out[base + 256 + tid] = (TO)(d1 * rs * sc[256 + tid] + bi[256 + tid]);
  out[base + 512 + tid] = (TO)(d2 * rs * sc[512 + tid] + bi[512 + tid]);
}

extern "C" void kernel_launch(void* const* d_in, const int* in_sizes, int n_in,
                              void* d_out, int out_size, void* d_ws, size_t ws_size,
                              hipStream_t stream) {
  (void)in_sizes; (void)n_in; (void)out_size; (void)ws_size;
  const float* x    = (const float*)d_in[0];
  const float* mask = (const float*)d_in[1];
  const float* Wq = (const float*)d_in[2];
  const float* bq = (const float*)d_in[3];
  const float* Wk = (const float*)d_in[4];
  const float* bk = (const float*)d_in[5];
  const float* Wv = (const float*)d_in[6];
  const float* bv = (const float*)d_in[7];
  const float* Wo = (const float*)d_in[8];
  const float* bo = (const float*)d_in[9];
  const float* W1 = (const float*)d_in[10];
  const float* b1 = (const float*)d_in[11];
  const float* W2 = (const float*)d_in[12];
  const float* b2 = (const float*)d_in[13];
  const float* ln1s = (const float*)d_in[14];
  const float* ln1b = (const float*)d_in[15];
  const float* ln2s = (const float*)d_in[16];
  const float* ln2b = (const float*)d_in[17];
  float* out = (float*)d_out;
  float* attn_out = out + 3145728;  // x2 is 2*2048*768

  // bf16 workspace layout (element offsets); hb overlays kb/vb/ctx (dead by then)
  bf16_t* ws  = (bf16_t*)d_ws;
  bf16_t* wqT = ws;                     // 589824  (wq/wk/wv contiguous = fused 2304x768)
  bf16_t* wkT = wqT + 589824;
  bf16_t* wvT = wkT + 589824;
  bf16_t* woT = wvT + 589824;
  bf16_t* w1T = woT + 589824;           // 2359296
  bf16_t* w2T = w1T + 2359296;          // 2359296
  bf16_t* xb  = w2T + 2359296;          // 3145728
  bf16_t* x1  = xb  + 3145728;          // 3145728
  bf16_t* qb  = x1  + 3145728;          // 3145728
  bf16_t* kb  = qb  + 3145728;          // 3145728
  bf16_t* vb  = kb  + 3145728;          // 3145728
  bf16_t* ctx = vb  + 3145728;          // 3145728
  bf16_t* hb  = kb;                     // FFN hidden overlays kb/vb/ctx + tail
  bf16_t* att = qb;                     // reuse (q dead after attention)
  bf16_t* yb  = qb;                     // reuse (att dead after ln1)

  // single launch for all four 768x768 weight transposes (saves 3 dispatch gaps)
  transpose_cvt4x_kernel<<<dim3(24, 24, 4), 256, 0, stream>>>(Wq, Wk, Wv, Wo,
                                                              wqT, wkT, wvT, woT);
  transpose_cvt_kernel<<<dim3(96, 24), 256, 0, stream>>>(W1, w1T, 768, 3072);
  transpose_cvt_kernel<<<dim3(24, 96), 256, 0, stream>>>(W2, w2T, 3072, 768);
  cvt4_kernel<<<3072, 256, 0, stream>>>(x, xb, 786432);

  dim3 blk(256);
  gemm_bt<3, 128><<<dim3(32, 18), blk, 0, stream>>>(xb, wqT, nullptr, nullptr, MROWS, 2304, 768,
                                                    qb, kb, vb, bq, bk, bv);
  attn_kernel<<<768, blk, 0, stream>>>(qb, kb, vb, mask, attn_out, ctx);
  gemm_bt<0, 64><<<dim3(32, 12), blk, 0, stream>>>(ctx, woT, bo, att, MROWS, 768, 768,
                                                   nullptr, nullptr, nullptr, nullptr, nullptr, nullptr);
  ln_res_kernel<float, bf16_t><<<MROWS, blk, 0, stream>>>(att, x, ln1s, ln1b, x1);
  gemm_bt<2, 128><<<dim3(32, 24), blk, 0, stream>>>(x1, w1T, b1, hb, MROWS, FFD, 768,
                                                    nullptr, nullptr, nullptr, nullptr, nullptr, nullptr);
  gemm_bt<0, 64><<<dim3(32, 12), blk, 0, stream>>>(hb, w2T, b2, yb, MROWS, 768, FFD,
                                                   nullptr, nullptr, nullptr, nullptr, nullptr, nullptr);
  ln_res_kernel<bf16_t, float><<<MROWS, blk, 0, stream>>>(yb, x1, ln2s, ln2b, out);
}

// Round 6
// 759.471 us; speedup vs baseline: 1.1077x; 1.0061x over previous
//
#include <hip/hip_runtime.h>
#include <stdint.h>

#define SS 2048
#define DD 768
#define HH 12
#define HDIM 64
#define FFD 3072
#define MROWS 4096  // B*S

typedef __bf16 bf16_t;
using bf16x4 = __attribute__((ext_vector_type(4))) __bf16;
using bf16x8 = __attribute__((ext_vector_type(8))) __bf16;
using f32x4  = __attribute__((ext_vector_type(4))) float;

__device__ inline float b2f(bf16_t v) { return (float)v; }
__device__ inline bf16_t f2b(float v) { return (bf16_t)v; }

// native v_exp_f32 (2^x). NOTE: __exp2f is NOT a HIP device intrinsic (glibc
// macro collision at compile time) — must use the amdgcn builtin.
__device__ inline float exp2_fast(float x) { return __builtin_amdgcn_exp2f(x); }

__device__ inline float gelu_f(float x) {
  float u = 0.7978845608028654f * (x + 0.044715f * x * x * x);
  float e = exp2_fast(2.8853900817779268f * u);  // e^{2u}; tanh(u)=1-2/(e+1)
  return x * (1.f - 1.f / (e + 1.f));            // == 0.5x(1+tanh(u))
}

// async global->LDS DMA, 16B per lane. LDS dest is wave-uniform base + lane*16.
typedef const __attribute__((address_space(1))) unsigned int* gas_u32;
typedef __attribute__((address_space(3))) unsigned int* las_u32;
__device__ inline void async_copy16(const void* g, void* l) {
  __builtin_amdgcn_global_load_lds((gas_u32)g, (las_u32)l, 16, 0, 0);
}

// ---------------- f32 -> bf16 convert, x4 vectorized ----------------
__global__ __launch_bounds__(256) void cvt4_kernel(
    const float* __restrict__ in, bf16_t* __restrict__ out, int n4) {
  int i = blockIdx.x * 256 + threadIdx.x;
  if (i >= n4) return;
  float4 v = ((const float4*)in)[i];
  bf16x4 o = {f2b(v.x), f2b(v.y), f2b(v.z), f2b(v.w)};
  ((bf16x4*)out)[i] = o;
}

// ---------------- tiled transpose+convert: out[N x K](bf16) = in[K x N](f32)^T ----------------
__global__ __launch_bounds__(256) void transpose_cvt_kernel(
    const float* __restrict__ in, bf16_t* __restrict__ out, int K, int N) {
  __shared__ float t[32][33];
  const int k0 = blockIdx.y * 32, n0 = blockIdx.x * 32;
  const int r = threadIdx.x >> 3, c4 = (threadIdx.x & 7) * 4;
  float4 v = *(const float4*)&in[(size_t)(k0 + r) * N + n0 + c4];
  t[r][c4 + 0] = v.x; t[r][c4 + 1] = v.y; t[r][c4 + 2] = v.z; t[r][c4 + 3] = v.w;
  __syncthreads();
  bf16x4 o = {f2b(t[c4 + 0][r]), f2b(t[c4 + 1][r]), f2b(t[c4 + 2][r]), f2b(t[c4 + 3][r])};
  *(bf16x4*)&out[(size_t)(n0 + r) * K + k0 + c4] = o;
}

// ---- 4x batched 768x768 transpose+convert (one launch, blockIdx.z selects matrix) ----
__global__ __launch_bounds__(256) void transpose_cvt4x_kernel(
    const float* __restrict__ s0, const float* __restrict__ s1,
    const float* __restrict__ s2, const float* __restrict__ s3,
    bf16_t* __restrict__ d0, bf16_t* __restrict__ d1,
    bf16_t* __restrict__ d2, bf16_t* __restrict__ d3) {
  __shared__ float t[32][33];
  const int z = blockIdx.z;
  const float* in = (z == 0) ? s0 : (z == 1) ? s1 : (z == 2) ? s2 : s3;
  bf16_t* out = (z == 0) ? d0 : (z == 1) ? d1 : (z == 2) ? d2 : d3;
  const int k0 = blockIdx.y * 32, n0 = blockIdx.x * 32;
  const int r = threadIdx.x >> 3, c4 = (threadIdx.x & 7) * 4;
  float4 v = *(const float4*)&in[(size_t)(k0 + r) * 768 + n0 + c4];
  t[r][c4 + 0] = v.x; t[r][c4 + 1] = v.y; t[r][c4 + 2] = v.z; t[r][c4 + 3] = v.w;
  __syncthreads();
  bf16x4 o = {f2b(t[c4 + 0][r]), f2b(t[c4 + 1][r]), f2b(t[c4 + 2][r]), f2b(t[c4 + 3][r])};
  *(bf16x4*)&out[(size_t)(n0 + r) * 768 + k0 + c4] = o;
}

// ---------------- GEMM: C[M,N] = A[M,K] @ Bt[N,K]^T + bias, epilogue ----------------
// EPI 0: bias only; EPI 2: gelu(val+bias); EPI 3: fused QKV (seg epilogue + rel bias on q,v)
// Staging via global_load_lds (m97 structure): 2 barriers/K-step, DMA direct to LDS.
template <int EPI, int BN>
__global__ __launch_bounds__(256) void gemm_bt(
    const bf16_t* __restrict__ A, const bf16_t* __restrict__ Bt,
    const float* __restrict__ bias, bf16_t* __restrict__ C,
    int M, int N, int K,
    bf16_t* __restrict__ q_out, bf16_t* __restrict__ k_out, bf16_t* __restrict__ v_out,
    const float* __restrict__ bqp, const float* __restrict__ bkp, const float* __restrict__ bvp) {
  __shared__ __align__(16) bf16_t ldsA[128 * 32];
  __shared__ __align__(16) bf16_t ldsB[BN * 32];
  const int tid = threadIdx.x;
  const int lane = tid & 63, wave = tid >> 6;
  const int quad = lane >> 4, lq = lane & 15;
  const int bm = blockIdx.x * 128, bn = blockIdx.y * BN;
  const int wm = (wave & 1) * 64;
  const int wn = (wave >> 1) * (BN / 2);
  constexpr int JT = BN / 32;  // col-tiles per wave

  f32x4 acc[4][JT] = {};

  const int srow = tid >> 2;       // 0..63
  const int scb = (tid & 3) * 16;  // byte offset within 64B k-row

#pragma unroll 1
  for (int k0 = 0; k0 < K; k0 += 32) {
    __syncthreads();  // prior iteration's ds_reads complete before DMA overwrite
    {
      const char* a0 = (const char*)A + ((size_t)(bm + srow) * K + k0) * 2 + scb;
      const char* a1 = (const char*)A + ((size_t)(bm + 64 + srow) * K + k0) * 2 + scb;
      async_copy16(a0, (char*)ldsA + wave * 1024);
      async_copy16(a1, (char*)ldsA + 4096 + wave * 1024);
#pragma unroll
      for (int bb = 0; bb < BN / 64; ++bb) {
        const char* bsrc = (const char*)Bt + ((size_t)(bn + bb * 64 + srow) * K + k0) * 2 + scb;
        async_copy16(bsrc, (char*)ldsB + bb * 4096 + wave * 1024);
      }
    }
    __syncthreads();  // compiler drains vmcnt(0) before barrier -> LDS valid
    bf16x8 af[4], bfr[JT];
#pragma unroll
    for (int i = 0; i < 4; ++i)
      af[i] = *(const bf16x8*)&ldsA[(wm + i * 16 + lq) * 32 + quad * 8];
#pragma unroll
    for (int j = 0; j < JT; ++j)
      bfr[j] = *(const bf16x8*)&ldsB[(wn + j * 16 + lq) * 32 + quad * 8];
#pragma unroll
    for (int i = 0; i < 4; ++i)
#pragma unroll
      for (int j = 0; j < JT; ++j)
        acc[i][j] = __builtin_amdgcn_mfma_f32_16x16x32_bf16(af[i], bfr[j], acc[i][j], 0, 0, 0);
  }

#pragma unroll
  for (int i = 0; i < 4; ++i) {
#pragma unroll
    for (int j = 0; j < JT; ++j) {
      const int n = bn + wn + j * 16 + lq;
      if (EPI == 3) {
        const int seg = n / 768;          // uniform within the 16-col group
        const int nc = n - seg * 768;
        bf16_t* op = (seg == 0) ? q_out : (seg == 1) ? k_out : v_out;
        const float* bp = (seg == 0) ? bqp : (seg == 1) ? bkp : bvp;
        const float bv_ = bp[nc];
#pragma unroll
        for (int r = 0; r < 4; ++r) {
          const int m = bm + wm + i * 16 + quad * 4 + r;
          float v = acc[i][j][r] + bv_;
          if (seg != 1) {
            float rel = (float)(nc - (m & 2047));
            v += fminf(fmaxf(rel, -3.f), 3.f);
          }
          op[(size_t)m * 768 + nc] = f2b(v);
        }
      } else {
        const float bv_ = bias[n];
#pragma unroll
        for (int r = 0; r < 4; ++r) {
          const int m = bm + wm + i * 16 + quad * 4 + r;
          float v = acc[i][j][r] + bv_;
          if (EPI == 2) v = gelu_f(v);
          C[(size_t)m * N + n] = f2b(v);
        }
      }
    }
  }
}

// ---------------- attention: 64 q-rows/block, 128-wide K-tiles ----------------
// Pass A restructured: 8 ct MFMAs batched into s[8] (back-to-back matrix-pipe
// issue), then EXACT tile-granularity online softmax (max tree + one rescale
// per tile) — cuts per-element VALU from ~10 ops to ~6 and removes the
// MFMA->VALU serialization. Pass B batches MFMAs the same way.
__global__ __launch_bounds__(256) void attn_kernel(
    const bf16_t* __restrict__ Q, const bf16_t* __restrict__ Km,
    const bf16_t* __restrict__ V, const float* __restrict__ mask,
    float* __restrict__ attn, bf16_t* __restrict__ ctx) {
  __shared__ __align__(16) bf16_t ldsK[128 * 68];     // [kpos][d], stride 68
  __shared__ __align__(16) bf16_t ldsVT[64 * 128];    // [d][kpos], XOR-swizzled
  __shared__ __align__(16) bf16_t ldsP[4][16 * 132];  // per-wave P, stride 132
  const int tid = threadIdx.x;
  const int lane = tid & 63, wave = tid >> 6;
  const int quad = lane >> 4, lq = lane & 15;
  const int qblk = blockIdx.x & 31, bh = blockIdx.x >> 5;
  const int b = bh / HH;
  const int qbase = qblk * 64 + wave * 16;

  const bf16_t* qh = Q + (size_t)bh * (SS * HDIM);
  const bf16_t* kh = Km + (size_t)bh * (SS * HDIM);
  const bf16_t* vh = V + (size_t)bh * (SS * HDIM);
  const float* mrow = mask + (size_t)b * SS * SS;

  // 1/sqrt(768) * log2(e): softmax computed base-2 (mask multiplies linearly,
  // so folding the base change into the scale commutes with it)
  const float scale2 = 0.03608439182435161f * 1.4426950408889634f;

  bf16x8 aq[2];
#pragma unroll
  for (int hf = 0; hf < 2; ++hf)
    aq[hf] = *(const bf16x8*)(qh + (size_t)(qbase + lq) * HDIM + hf * 32 + quad * 8);

  const int srow = tid >> 3;       // 0..31 per round
  const int sc8 = (tid & 7) * 8;   // element offset within 64-wide row

  float mrun[4], lrun[4];
#pragma unroll
  for (int r = 0; r < 4; ++r) { mrun[r] = -1e30f; lrun[r] = 0.f; }

  // -------- pass A: exact online (max, sumexp2), tile-granular update --------
  bf16x8 kvv[4];
#pragma unroll
  for (int rd = 0; rd < 4; ++rd)
    kvv[rd] = *(const bf16x8*)(kh + (size_t)(rd * 32 + srow) * HDIM + sc8);

#pragma unroll 1
  for (int kt = 0; kt < 16; ++kt) {
    const int kbase = kt * 128;
    __syncthreads();
#pragma unroll
    for (int rd = 0; rd < 4; ++rd)
      *(bf16x8*)&ldsK[(rd * 32 + srow) * 68 + sc8] = kvv[rd];
    __syncthreads();
    // prefetch next K tile under this tile's compute
    if (kt < 15) {
#pragma unroll
      for (int rd = 0; rd < 4; ++rd)
        kvv[rd] = *(const bf16x8*)(kh + (size_t)(kbase + 128 + rd * 32 + srow) * HDIM + sc8);
    }
    // hoisted mask loads: 32 independent dwords, batch-issued once per tile
    float mk[8][4];
#pragma unroll
    for (int ct = 0; ct < 8; ++ct)
#pragma unroll
      for (int r = 0; r < 4; ++r)
        mk[ct][r] = mrow[(size_t)(qbase + quad * 4 + r) * SS + kbase + ct * 16 + lq];
    // batch all 8 ct MFMAs (back-to-back matrix-pipe issue)
    f32x4 s[8];
#pragma unroll
    for (int ct = 0; ct < 8; ++ct) {
      bf16x8 bk0 = *(const bf16x8*)&ldsK[(ct * 16 + lq) * 68 + quad * 8];
      bf16x8 bk1 = *(const bf16x8*)&ldsK[(ct * 16 + lq) * 68 + 32 + quad * 8];
      f32x4 t = {};
      t = __builtin_amdgcn_mfma_f32_16x16x32_bf16(aq[0], bk0, t, 0, 0, 0);
      t = __builtin_amdgcn_mfma_f32_16x16x32_bf16(aq[1], bk1, t, 0, 0, 0);
      s[ct] = t;
    }
    // exact block-online-softmax: one max tree + one rescale per tile per row
#pragma unroll
    for (int r = 0; r < 4; ++r) {
      float sv[8];
#pragma unroll
      for (int ct = 0; ct < 8; ++ct) sv[ct] = s[ct][r] * scale2 * mk[ct][r];
      float t01 = fmaxf(sv[0], sv[1]), t23 = fmaxf(sv[2], sv[3]);
      float t45 = fmaxf(sv[4], sv[5]), t67 = fmaxf(sv[6], sv[7]);
      float tmax = fmaxf(fmaxf(t01, t23), fmaxf(t45, t67));
      float nm = fmaxf(mrun[r], tmax);
      float a0 = 0.f;
#pragma unroll
      for (int ct = 0; ct < 8; ++ct) a0 += exp2_fast(sv[ct] - nm);
      lrun[r] = lrun[r] * exp2_fast(mrun[r] - nm) + a0;
      mrun[r] = nm;
    }
  }
#pragma unroll
  for (int xm = 1; xm <= 8; xm <<= 1) {
#pragma unroll
    for (int r = 0; r < 4; ++r) {
      float mo = __shfl_xor(mrun[r], xm);
      float lo = __shfl_xor(lrun[r], xm);
      float mm = fmaxf(mrun[r], mo);
      lrun[r] = lrun[r] * exp2_fast(mrun[r] - mm) + lo * exp2_fast(mo - mm);
      mrun[r] = mm;
    }
  }
  float linv[4];
#pragma unroll
  for (int r = 0; r < 4; ++r) linv[r] = 1.f / lrun[r];

  // -------- pass B: P = exp2(s-m)/l, write attn (f32), O += P@V --------
  f32x4 oacc[4] = {};
  float* attnrow = attn + (size_t)bh * SS * SS;

  bf16x8 vvv[4];
#pragma unroll
  for (int rd = 0; rd < 4; ++rd) {
    kvv[rd] = *(const bf16x8*)(kh + (size_t)(rd * 32 + srow) * HDIM + sc8);
    vvv[rd] = *(const bf16x8*)(vh + (size_t)(rd * 32 + srow) * HDIM + sc8);
  }

#pragma unroll 1
  for (int kt = 0; kt < 16; ++kt) {
    const int kbase = kt * 128;
    __syncthreads();
#pragma unroll
    for (int rd = 0; rd < 4; ++rd) {
      const int row = rd * 32 + srow;
      *(bf16x8*)&ldsK[row * 68 + sc8] = kvv[rd];
      // V transpose write, XOR-swizzled with ((d>>3)^d)&7: per-instruction the
      // write spreads by tid&7 (2-way free); the PV read spreads by lq&7^lq>>3
      // (all 8 bank-groups covered).
#pragma unroll
      for (int j = 0; j < 8; ++j) {
        const int d = sc8 + j;
        const unsigned wbyte =
            (unsigned)(d * 256 + row * 2) ^ (unsigned)((((d >> 3) ^ d) & 7) << 4);
        *(bf16_t*)((char*)ldsVT + wbyte) = vvv[rd][j];
      }
    }
    __syncthreads();
    // prefetch next K/V tile under this tile's compute
    if (kt < 15) {
#pragma unroll
      for (int rd = 0; rd < 4; ++rd) {
        kvv[rd] = *(const bf16x8*)(kh + (size_t)(kbase + 128 + rd * 32 + srow) * HDIM + sc8);
        vvv[rd] = *(const bf16x8*)(vh + (size_t)(kbase + 128 + rd * 32 + srow) * HDIM + sc8);
      }
    }
    float mk[8][4];
#pragma unroll
    for (int ct = 0; ct < 8; ++ct)
#pragma unroll
      for (int r = 0; r < 4; ++r)
        mk[ct][r] = mrow[(size_t)(qbase + quad * 4 + r) * SS + kbase + ct * 16 + lq];
    // batch MFMAs, then apply softmax and stage P
    f32x4 s[8];
#pragma unroll
    for (int ct = 0; ct < 8; ++ct) {
      bf16x8 bk0 = *(const bf16x8*)&ldsK[(ct * 16 + lq) * 68 + quad * 8];
      bf16x8 bk1 = *(const bf16x8*)&ldsK[(ct * 16 + lq) * 68 + 32 + quad * 8];
      f32x4 t = {};
      t = __builtin_amdgcn_mfma_f32_16x16x32_bf16(aq[0], bk0, t, 0, 0, 0);
      t = __builtin_amdgcn_mfma_f32_16x16x32_bf16(aq[1], bk1, t, 0, 0, 0);
      s[ct] = t;
    }
#pragma unroll
    for (int ct = 0; ct < 8; ++ct) {
#pragma unroll
      for (int r = 0; r < 4; ++r) {
        float sv = s[ct][r] * scale2 * mk[ct][r];
        float p = exp2_fast(sv - mrun[r]) * linv[r];
        ldsP[wave][(quad * 4 + r) * 132 + ct * 16 + lq] = f2b(p);
      }
    }
    asm volatile("s_waitcnt lgkmcnt(0)" ::: "memory");
    // coalesced f32 attn store from wave-private P tile
#pragma unroll
    for (int rnd = 0; rnd < 4; ++rnd) {
      const int c = rnd * 64 + lane;
      const int prow = c >> 4, pc = c & 15;
      bf16x8 pv = *(const bf16x8*)&ldsP[wave][prow * 132 + pc * 8];
      float4 f0 = {b2f(pv[0]), b2f(pv[1]), b2f(pv[2]), b2f(pv[3])};
      float4 f1 = {b2f(pv[4]), b2f(pv[5]), b2f(pv[6]), b2f(pv[7])};
      float* dst = attnrow + (size_t)(qbase + prow) * SS + kbase + pc * 8;
      *(float4*)dst = f0;
      *(float4*)(dst + 4) = f1;
    }
    // O += P @ V
#pragma unroll
    for (int kc = 0; kc < 4; ++kc) {
      bf16x8 pf = *(const bf16x8*)&ldsP[wave][lq * 132 + kc * 32 + quad * 8];
#pragma unroll
      for (int dt = 0; dt < 4; ++dt) {
        const int vd = dt * 16 + lq;
        const unsigned vbyte = (unsigned)(vd * 256 + (kc * 32 + quad * 8) * 2) ^
                               (unsigned)((((vd >> 3) ^ vd) & 7) << 4);
        bf16x8 vf = *(const bf16x8*)((const char*)ldsVT + vbyte);
        oacc[dt] = __builtin_amdgcn_mfma_f32_16x16x32_bf16(pf, vf, oacc[dt], 0, 0, 0);
      }
    }
  }

  bf16_t* ch = ctx + (size_t)bh * (SS * HDIM);
#pragma unroll
  for (int dt = 0; dt < 4; ++dt)
#pragma unroll
    for (int r = 0; r < 4; ++r)
      ch[(size_t)(qbase + quad * 4 + r) * HDIM + dt * 16 + lq] = f2b(oacc[dt][r]);
}

// ---------------- residual + LayerNorm over 768 ----------------
template <typename TR, typename TO>
__global__ __launch_bounds__(256) void ln_res_kernel(
    const bf16_t* __restrict__ a, const TR* __restrict__ res,
    const float* __restrict__ sc, const float* __restrict__ bi,
    TO* __restrict__ out) {
  __shared__ float red[8];
  const int row = blockIdx.x, tid = threadIdx.x;
  const size_t base = (size_t)row * DD;
  float v0 = b2f(a[base + tid]) + (float)res[base + tid];
  float v1 = b2f(a[base + 256 + tid]) + (float)res[base + 256 + tid];
  float v2 = b2f(a[base + 512 + tid]) + (float)res[base + 512 + tid];
  float s = v0 + v1 + v2;
#pragma unroll
  for (int o = 32; o; o >>= 1) s += __shfl_down(s, o, 64);
  if ((tid & 63) == 0) red[tid >> 6] = s;
  __syncthreads();
  const float mean = (red[0] + red[1] + red[2] + red[3]) * (1.f / 768.f);
  const float d0 = v0 - mean, d1 = v1 - mean, d2 = v2 - mean;
  float q = d0 * d0 + d1 * d1 + d2 * d2;
#pragma unroll
  for (int o = 32; o; o >>= 1) q += __shfl_down(q, o, 64);
  if ((tid & 63) == 0) red[4 + (tid >> 6)] = q;
  __syncthreads();
  const float var = (red[4] + red[5] + red[6] + red[7]) * (1.f / 768.f);
  const float rs = rsqrtf(var + 1e-6f);
  out[base + tid]       = (TO)(d0 * rs * sc[tid]       + bi[tid]);
  out[base + 256 + tid] = (TO)(d1 * rs * sc[256 + tid] + bi[256 + tid]);
  out[base + 512 + tid] = (TO)(d2 * rs * sc[512 + tid] + bi[512 + tid]);
}

extern "C" void kernel_launch(void* const* d_in, const int* in_sizes, int n_in,
                              void* d_out, int out_size, void* d_ws, size_t ws_size,
                              hipStream_t stream) {
  (void)in_sizes; (void)n_in; (void)out_size; (void)ws_size;
  const float* x    = (const float*)d_in[0];
  const float* mask = (const float*)d_in[1];
  const float* Wq = (const float*)d_in[2];
  const float* bq = (const float*)d_in[3];
  const float* Wk = (const float*)d_in[4];
  const float* bk = (const float*)d_in[5];
  const float* Wv = (const float*)d_in[6];
  const float* bv = (const float*)d_in[7];
  const float* Wo = (const float*)d_in[8];
  const float* bo = (const float*)d_in[9];
  const float* W1 = (const float*)d_in[10];
  const float* b1 = (const float*)d_in[11];
  const float* W2 = (const float*)d_in[12];
  const float* b2 = (const float*)d_in[13];
  const float* ln1s = (const float*)d_in[14];
  const float* ln1b = (const float*)d_in[15];
  const float* ln2s = (const float*)d_in[16];
  const float* ln2b = (const float*)d_in[17];
  float* out = (float*)d_out;
  float* attn_out = out + 3145728;  // x2 is 2*2048*768

  // bf16 workspace layout (element offsets); hb overlays kb/vb/ctx (dead by then)
  bf16_t* ws  = (bf16_t*)d_ws;
  bf16_t* wqT = ws;                     // 589824  (wq/wk/wv contiguous = fused 2304x768)
  bf16_t* wkT = wqT + 589824;
  bf16_t* wvT = wkT + 589824;
  bf16_t* woT = wvT + 589824;
  bf16_t* w1T = woT + 589824;           // 2359296
  bf16_t* w2T = w1T + 2359296;          // 2359296
  bf16_t* xb  = w2T + 2359296;          // 3145728
  bf16_t* x1  = xb  + 3145728;          // 3145728
  bf16_t* qb  = x1  + 3145728;          // 3145728
  bf16_t* kb  = qb  + 3145728;          // 3145728
  bf16_t* vb  = kb  + 3145728;          // 3145728
  bf16_t* ctx = vb  + 3145728;          // 3145728
  bf16_t* hb  = kb;                     // FFN hidden overlays kb/vb/ctx + tail
  bf16_t* att = qb;                     // reuse (q dead after attention)
  bf16_t* yb  = qb;                     // reuse (att dead after ln1)

  // single launch for all four 768x768 weight transposes (saves 3 dispatch gaps)
  transpose_cvt4x_kernel<<<dim3(24, 24, 4), 256, 0, stream>>>(Wq, Wk, Wv, Wo,
                                                              wqT, wkT, wvT, woT);
  transpose_cvt_kernel<<<dim3(96, 24), 256, 0, stream>>>(W1, w1T, 768, 3072);
  transpose_cvt_kernel<<<dim3(24, 96), 256, 0, stream>>>(W2, w2T, 3072, 768);
  cvt4_kernel<<<3072, 256, 0, stream>>>(x, xb, 786432);

  dim3 blk(256);
  gemm_bt<3, 128><<<dim3(32, 18), blk, 0, stream>>>(xb, wqT, nullptr, nullptr, MROWS, 2304, 768,
                                                    qb, kb, vb, bq, bk, bv);
  attn_kernel<<<768, blk, 0, stream>>>(qb, kb, vb, mask, attn_out, ctx);
  gemm_bt<0, 64><<<dim3(32, 12), blk, 0, stream>>>(ctx, woT, bo, att, MROWS, 768, 768,
                                                   nullptr, nullptr, nullptr, nullptr, nullptr, nullptr);
  ln_res_kernel<float, bf16_t><<<MROWS, blk, 0, stream>>>(att, x, ln1s, ln1b, x1);
  gemm_bt<2, 128><<<dim3(32, 24), blk, 0, stream>>>(x1, w1T, b1, hb, MROWS, FFD, 768,
                                                    nullptr, nullptr, nullptr, nullptr, nullptr, nullptr);
  gemm_bt<0, 64><<<dim3(32, 12), blk, 0, stream>>>(hb, w2T, b2, yb, MROWS, 768, FFD,
                                                   nullptr, nullptr, nullptr, nullptr, nullptr, nullptr);
  ln_res_kernel<bf16_t, float><<<MROWS, blk, 0, stream>>>(yb, x1, ln2s, ln2b, out);
}

// Round 10
// 743.131 us; speedup vs baseline: 1.1321x; 1.0220x over previous
//
#include <hip/hip_runtime.h>
#include <stdint.h>

#define SS 2048
#define DD 768
#define HH 12
#define HDIM 64
#define FFD 3072
#define MROWS 4096  // B*S

typedef __bf16 bf16_t;
using bf16x4 = __attribute__((ext_vector_type(4))) __bf16;
using bf16x8 = __attribute__((ext_vector_type(8))) __bf16;
using f32x4  = __attribute__((ext_vector_type(4))) float;

__device__ inline float b2f(bf16_t v) { return (float)v; }
__device__ inline bf16_t f2b(float v) { return (bf16_t)v; }

// native v_exp_f32 (2^x). NOTE: __exp2f is NOT a HIP device intrinsic (glibc
// macro collision at compile time) — must use the amdgcn builtin.
__device__ inline float exp2_fast(float x) { return __builtin_amdgcn_exp2f(x); }

__device__ inline float gelu_f(float x) {
  float u = 0.7978845608028654f * (x + 0.044715f * x * x * x);
  float e = exp2_fast(2.8853900817779268f * u);  // e^{2u}; tanh(u)=1-2/(e+1)
  return x * (1.f - 1.f / (e + 1.f));            // == 0.5x(1+tanh(u))
}

// async global->LDS DMA, 16B per lane. LDS dest is wave-uniform base + lane*16.
typedef const __attribute__((address_space(1))) unsigned int* gas_u32;
typedef __attribute__((address_space(3))) unsigned int* las_u32;
__device__ inline void async_copy16(const void* g, void* l) {
  __builtin_amdgcn_global_load_lds((gas_u32)g, (las_u32)l, 16, 0, 0);
}

// ---------------- f32 -> bf16 convert, x4 vectorized ----------------
__global__ __launch_bounds__(256) void cvt4_kernel(
    const float* __restrict__ in, bf16_t* __restrict__ out, int n4) {
  int i = blockIdx.x * 256 + threadIdx.x;
  if (i >= n4) return;
  float4 v = ((const float4*)in)[i];
  bf16x4 o = {f2b(v.x), f2b(v.y), f2b(v.z), f2b(v.w)};
  ((bf16x4*)out)[i] = o;
}

// ---------------- tiled transpose+convert: out[N x K](bf16) = in[K x N](f32)^T ----------------
__global__ __launch_bounds__(256) void transpose_cvt_kernel(
    const float* __restrict__ in, bf16_t* __restrict__ out, int K, int N) {
  __shared__ float t[32][33];
  const int k0 = blockIdx.y * 32, n0 = blockIdx.x * 32;
  const int r = threadIdx.x >> 3, c4 = (threadIdx.x & 7) * 4;
  float4 v = *(const float4*)&in[(size_t)(k0 + r) * N + n0 + c4];
  t[r][c4 + 0] = v.x; t[r][c4 + 1] = v.y; t[r][c4 + 2] = v.z; t[r][c4 + 3] = v.w;
  __syncthreads();
  bf16x4 o = {f2b(t[c4 + 0][r]), f2b(t[c4 + 1][r]), f2b(t[c4 + 2][r]), f2b(t[c4 + 3][r])};
  *(bf16x4*)&out[(size_t)(n0 + r) * K + k0 + c4] = o;
}

// ---- 4x batched 768x768 transpose+convert (one launch, blockIdx.z selects matrix) ----
__global__ __launch_bounds__(256) void transpose_cvt4x_kernel(
    const float* __restrict__ s0, const float* __restrict__ s1,
    const float* __restrict__ s2, const float* __restrict__ s3,
    bf16_t* __restrict__ d0, bf16_t* __restrict__ d1,
    bf16_t* __restrict__ d2, bf16_t* __restrict__ d3) {
  __shared__ float t[32][33];
  const int z = blockIdx.z;
  const float* in = (z == 0) ? s0 : (z == 1) ? s1 : (z == 2) ? s2 : s3;
  bf16_t* out = (z == 0) ? d0 : (z == 1) ? d1 : (z == 2) ? d2 : d3;
  const int k0 = blockIdx.y * 32, n0 = blockIdx.x * 32;
  const int r = threadIdx.x >> 3, c4 = (threadIdx.x & 7) * 4;
  float4 v = *(const float4*)&in[(size_t)(k0 + r) * 768 + n0 + c4];
  t[r][c4 + 0] = v.x; t[r][c4 + 1] = v.y; t[r][c4 + 2] = v.z; t[r][c4 + 3] = v.w;
  __syncthreads();
  bf16x4 o = {f2b(t[c4 + 0][r]), f2b(t[c4 + 1][r]), f2b(t[c4 + 2][r]), f2b(t[c4 + 3][r])};
  *(bf16x4*)&out[(size_t)(n0 + r) * 768 + k0 + c4] = o;
}

// ---------------- GEMM: C[M,N] = A[M,K] @ Bt[N,K]^T + bias, epilogue ----------------
// EPI 0: bias only; EPI 2: gelu(val+bias); EPI 3: fused QKV (seg epilogue + rel bias on q,v)
// T3 minimum-2-phase pipeline: double-buffered LDS, next tile's global_load_lds
// issued BEFORE current tile's compute; ONE barrier per K-step (its implicit
// vmcnt(0) drain lands after ds_read+MFMA have covered the DMA latency).
template <int EPI, int BN>
__global__ __launch_bounds__(256) void gemm_bt(
    const bf16_t* __restrict__ A, const bf16_t* __restrict__ Bt,
    const float* __restrict__ bias, bf16_t* __restrict__ C,
    int M, int N, int K,
    bf16_t* __restrict__ q_out, bf16_t* __restrict__ k_out, bf16_t* __restrict__ v_out,
    const float* __restrict__ bqp, const float* __restrict__ bkp, const float* __restrict__ bvp) {
  __shared__ __align__(16) bf16_t ldsA[2][128 * 32];
  __shared__ __align__(16) bf16_t ldsB[2][BN * 32];
  const int tid = threadIdx.x;
  const int lane = tid & 63, wave = tid >> 6;
  const int quad = lane >> 4, lq = lane & 15;
  const int bm = blockIdx.x * 128, bn = blockIdx.y * BN;
  const int wm = (wave & 1) * 64;
  const int wn = (wave >> 1) * (BN / 2);
  constexpr int JT = BN / 32;  // col-tiles per wave

  f32x4 acc[4][JT] = {};

  const int srow = tid >> 2;       // 0..63
  const int scb = (tid & 3) * 16;  // byte offset within 64B k-row

  // per-thread global base offsets (k0 added per tile)
  const char* aptr0 = (const char*)A + (size_t)(bm + srow) * K * 2 + scb;
  const char* aptr1 = (const char*)A + (size_t)(bm + 64 + srow) * K * 2 + scb;

#define STAGE_TILE(buf, kk)                                                      \
  do {                                                                           \
    async_copy16(aptr0 + (size_t)(kk) * 2, (char*)ldsA[buf] + tid * 16);         \
    async_copy16(aptr1 + (size_t)(kk) * 2, (char*)ldsA[buf] + 4096 + tid * 16);  \
    _Pragma("unroll") for (int bb = 0; bb < BN / 64; ++bb) {                     \
      const char* bsrc =                                                         \
          (const char*)Bt + ((size_t)(bn + bb * 64 + srow) * K + (kk)) * 2 + scb;\
      async_copy16(bsrc, (char*)ldsB[buf] + bb * 4096 + tid * 16);               \
    }                                                                            \
  } while (0)

  STAGE_TILE(0, 0);
  __syncthreads();  // drains vmcnt(0): tile 0 resident
  int cur = 0;

#pragma unroll 1
  for (int k0 = 0; k0 < K; k0 += 32) {
    if (k0 + 32 < K) STAGE_TILE(cur ^ 1, k0 + 32);  // next tile in flight under compute
    bf16x8 af[4], bfr[JT];
#pragma unroll
    for (int i = 0; i < 4; ++i)
      af[i] = *(const bf16x8*)&ldsA[cur][(wm + i * 16 + lq) * 32 + quad * 8];
#pragma unroll
    for (int j = 0; j < JT; ++j)
      bfr[j] = *(const bf16x8*)&ldsB[cur][(wn + j * 16 + lq) * 32 + quad * 8];
#pragma unroll
    for (int i = 0; i < 4; ++i)
#pragma unroll
      for (int j = 0; j < JT; ++j)
        acc[i][j] = __builtin_amdgcn_mfma_f32_16x16x32_bf16(af[i], bfr[j], acc[i][j], 0, 0, 0);
    __syncthreads();  // one barrier/K-step: drains next-tile DMA + all reads done
    cur ^= 1;
  }
#undef STAGE_TILE

#pragma unroll
  for (int i = 0; i < 4; ++i) {
#pragma unroll
    for (int j = 0; j < JT; ++j) {
      const int n = bn + wn + j * 16 + lq;
      if (EPI == 3) {
        const int seg = n / 768;          // uniform within the 16-col group
        const int nc = n - seg * 768;
        bf16_t* op = (seg == 0) ? q_out : (seg == 1) ? k_out : v_out;
        const float* bp = (seg == 0) ? bqp : (seg == 1) ? bkp : bvp;
        const float bv_ = bp[nc];
#pragma unroll
        for (int r = 0; r < 4; ++r) {
          const int m = bm + wm + i * 16 + quad * 4 + r;
          float v = acc[i][j][r] + bv_;
          if (seg != 1) {
            float rel = (float)(nc - (m & 2047));
            v += fminf(fmaxf(rel, -3.f), 3.f);
          }
          op[(size_t)m * 768 + nc] = f2b(v);
        }
      } else {
        const float bv_ = bias[n];
#pragma unroll
        for (int r = 0; r < 4; ++r) {
          const int m = bm + wm + i * 16 + quad * 4 + r;
          float v = acc[i][j][r] + bv_;
          if (EPI == 2) v = gelu_f(v);
          C[(size_t)m * N + n] = f2b(v);
        }
      }
    }
  }
}

// ---------------- attention: 64 q-rows/block, 128-wide K-tiles ----------------
// (unchanged this round — single-variable discipline)
__global__ __launch_bounds__(256) void attn_kernel(
    const bf16_t* __restrict__ Q, const bf16_t* __restrict__ Km,
    const bf16_t* __restrict__ V, const float* __restrict__ mask,
    float* __restrict__ attn, bf16_t* __restrict__ ctx) {
  __shared__ __align__(16) bf16_t ldsK[128 * 68];     // [kpos][d], stride 68
  __shared__ __align__(16) bf16_t ldsVT[64 * 128];    // [d][kpos], XOR-swizzled
  __shared__ __align__(16) bf16_t ldsP[4][16 * 132];  // per-wave P, stride 132
  const int tid = threadIdx.x;
  const int lane = tid & 63, wave = tid >> 6;
  const int quad = lane >> 4, lq = lane & 15;
  const int qblk = blockIdx.x & 31, bh = blockIdx.x >> 5;
  const int b = bh / HH;
  const int qbase = qblk * 64 + wave * 16;

  const bf16_t* qh = Q + (size_t)bh * (SS * HDIM);
  const bf16_t* kh = Km + (size_t)bh * (SS * HDIM);
  const bf16_t* vh = V + (size_t)bh * (SS * HDIM);
  const float* mrow = mask + (size_t)b * SS * SS;

  // 1/sqrt(768) * log2(e): softmax computed base-2 (mask multiplies linearly,
  // so folding the base change into the scale commutes with it)
  const float scale2 = 0.03608439182435161f * 1.4426950408889634f;

  bf16x8 aq[2];
#pragma unroll
  for (int hf = 0; hf < 2; ++hf)
    aq[hf] = *(const bf16x8*)(qh + (size_t)(qbase + lq) * HDIM + hf * 32 + quad * 8);

  const int srow = tid >> 3;       // 0..31 per round
  const int sc8 = (tid & 7) * 8;   // element offset within 64-wide row

  float mrun[4], lrun[4];
#pragma unroll
  for (int r = 0; r < 4; ++r) { mrun[r] = -1e30f; lrun[r] = 0.f; }

  // -------- pass A: exact online (max, sumexp2), tile-granular update --------
  bf16x8 kvv[4];
#pragma unroll
  for (int rd = 0; rd < 4; ++rd)
    kvv[rd] = *(const bf16x8*)(kh + (size_t)(rd * 32 + srow) * HDIM + sc8);

#pragma unroll 1
  for (int kt = 0; kt < 16; ++kt) {
    const int kbase = kt * 128;
    __syncthreads();
#pragma unroll
    for (int rd = 0; rd < 4; ++rd)
      *(bf16x8*)&ldsK[(rd * 32 + srow) * 68 + sc8] = kvv[rd];
    __syncthreads();
    // prefetch next K tile under this tile's compute
    if (kt < 15) {
#pragma unroll
      for (int rd = 0; rd < 4; ++rd)
        kvv[rd] = *(const bf16x8*)(kh + (size_t)(kbase + 128 + rd * 32 + srow) * HDIM + sc8);
    }
    // hoisted mask loads: 32 independent dwords, batch-issued once per tile
    float mk[8][4];
#pragma unroll
    for (int ct = 0; ct < 8; ++ct)
#pragma unroll
      for (int r = 0; r < 4; ++r)
        mk[ct][r] = mrow[(size_t)(qbase + quad * 4 + r) * SS + kbase + ct * 16 + lq];
    // batch all 8 ct MFMAs (back-to-back matrix-pipe issue)
    f32x4 s[8];
#pragma unroll
    for (int ct = 0; ct < 8; ++ct) {
      bf16x8 bk0 = *(const bf16x8*)&ldsK[(ct * 16 + lq) * 68 + quad * 8];
      bf16x8 bk1 = *(const bf16x8*)&ldsK[(ct * 16 + lq) * 68 + 32 + quad * 8];
      f32x4 t = {};
      t = __builtin_amdgcn_mfma_f32_16x16x32_bf16(aq[0], bk0, t, 0, 0, 0);
      t = __builtin_amdgcn_mfma_f32_16x16x32_bf16(aq[1], bk1, t, 0, 0, 0);
      s[ct] = t;
    }
    // exact block-online-softmax: one max tree + one rescale per tile per row
#pragma unroll
    for (int r = 0; r < 4; ++r) {
      float sv[8];
#pragma unroll
      for (int ct = 0; ct < 8; ++ct) sv[ct] = s[ct][r] * scale2 * mk[ct][r];
      float t01 = fmaxf(sv[0], sv[1]), t23 = fmaxf(sv[2], sv[3]);
      float t45 = fmaxf(sv[4], sv[5]), t67 = fmaxf(sv[6], sv[7]);
      float tmax = fmaxf(fmaxf(t01, t23), fmaxf(t45, t67));
      float nm = fmaxf(mrun[r], tmax);
      float a0 = 0.f;
#pragma unroll
      for (int ct = 0; ct < 8; ++ct) a0 += exp2_fast(sv[ct] - nm);
      lrun[r] = lrun[r] * exp2_fast(mrun[r] - nm) + a0;
      mrun[r] = nm;
    }
  }
#pragma unroll
  for (int xm = 1; xm <= 8; xm <<= 1) {
#pragma unroll
    for (int r = 0; r < 4; ++r) {
      float mo = __shfl_xor(mrun[r], xm);
      float lo = __shfl_xor(lrun[r], xm);
      float mm = fmaxf(mrun[r], mo);
      lrun[r] = lrun[r] * exp2_fast(mrun[r] - mm) + lo * exp2_fast(mo - mm);
      mrun[r] = mm;
    }
  }
  float linv[4];
#pragma unroll
  for (int r = 0; r < 4; ++r) linv[r] = 1.f / lrun[r];

  // -------- pass B: P = exp2(s-m)/l, write attn (f32), O += P@V --------
  f32x4 oacc[4] = {};
  float* attnrow = attn + (size_t)bh * SS * SS;

  bf16x8 vvv[4];
#pragma unroll
  for (int rd = 0; rd < 4; ++rd) {
    kvv[rd] = *(const bf16x8*)(kh + (size_t)(rd * 32 + srow) * HDIM + sc8);
    vvv[rd] = *(const bf16x8*)(vh + (size_t)(rd * 32 + srow) * HDIM + sc8);
  }

#pragma unroll 1
  for (int kt = 0; kt < 16; ++kt) {
    const int kbase = kt * 128;
    __syncthreads();
#pragma unroll
    for (int rd = 0; rd < 4; ++rd) {
      const int row = rd * 32 + srow;
      *(bf16x8*)&ldsK[row * 68 + sc8] = kvv[rd];
      // V transpose write, XOR-swizzled with ((d>>3)^d)&7: per-instruction the
      // write spreads by tid&7 (2-way free); the PV read spreads by lq&7^lq>>3
      // (all 8 bank-groups covered).
#pragma unroll
      for (int j = 0; j < 8; ++j) {
        const int d = sc8 + j;
        const unsigned wbyte =
            (unsigned)(d * 256 + row * 2) ^ (unsigned)((((d >> 3) ^ d) & 7) << 4);
        *(bf16_t*)((char*)ldsVT + wbyte) = vvv[rd][j];
      }
    }
    __syncthreads();
    // prefetch next K/V tile under this tile's compute
    if (kt < 15) {
#pragma unroll
      for (int rd = 0; rd < 4; ++rd) {
        kvv[rd] = *(const bf16x8*)(kh + (size_t)(kbase + 128 + rd * 32 + srow) * HDIM + sc8);
        vvv[rd] = *(const bf16x8*)(vh + (size_t)(kbase + 128 + rd * 32 + srow) * HDIM + sc8);
      }
    }
    float mk[8][4];
#pragma unroll
    for (int ct = 0; ct < 8; ++ct)
#pragma unroll
      for (int r = 0; r < 4; ++r)
        mk[ct][r] = mrow[(size_t)(qbase + quad * 4 + r) * SS + kbase + ct * 16 + lq];
    // batch MFMAs, then apply softmax and stage P
    f32x4 s[8];
#pragma unroll
    for (int ct = 0; ct < 8; ++ct) {
      bf16x8 bk0 = *(const bf16x8*)&ldsK[(ct * 16 + lq) * 68 + quad * 8];
      bf16x8 bk1 = *(const bf16x8*)&ldsK[(ct * 16 + lq) * 68 + 32 + quad * 8];
      f32x4 t = {};
      t = __builtin_amdgcn_mfma_f32_16x16x32_bf16(aq[0], bk0, t, 0, 0, 0);
      t = __builtin_amdgcn_mfma_f32_16x16x32_bf16(aq[1], bk1, t, 0, 0, 0);
      s[ct] = t;
    }
#pragma unroll
    for (int ct = 0; ct < 8; ++ct) {
#pragma unroll
      for (int r = 0; r < 4; ++r) {
        float sv = s[ct][r] * scale2 * mk[ct][r];
        float p = exp2_fast(sv - mrun[r]) * linv[r];
        ldsP[wave][(quad * 4 + r) * 132 + ct * 16 + lq] = f2b(p);
      }
    }
    asm volatile("s_waitcnt lgkmcnt(0)" ::: "memory");
    // coalesced f32 attn store from wave-private P tile
#pragma unroll
    for (int rnd = 0; rnd < 4; ++rnd) {
      const int c = rnd * 64 + lane;
      const int prow = c >> 4, pc = c & 15;
      bf16x8 pv = *(const bf16x8*)&ldsP[wave][prow * 132 + pc * 8];
      float4 f0 = {b2f(pv[0]), b2f(pv[1]), b2f(pv[2]), b2f(pv[3])};
      float4 f1 = {b2f(pv[4]), b2f(pv[5]), b2f(pv[6]), b2f(pv[7])};
      float* dst = attnrow + (size_t)(qbase + prow) * SS + kbase + pc * 8;
      *(float4*)dst = f0;
      *(float4*)(dst + 4) = f1;
    }
    // O += P @ V
#pragma unroll
    for (int kc = 0; kc < 4; ++kc) {
      bf16x8 pf = *(const bf16x8*)&ldsP[wave][lq * 132 + kc * 32 + quad * 8];
#pragma unroll
      for (int dt = 0; dt < 4; ++dt) {
        const int vd = dt * 16 + lq;
        const unsigned vbyte = (unsigned)(vd * 256 + (kc * 32 + quad * 8) * 2) ^
                               (unsigned)((((vd >> 3) ^ vd) & 7) << 4);
        bf16x8 vf = *(const bf16x8*)((const char*)ldsVT + vbyte);
        oacc[dt] = __builtin_amdgcn_mfma_f32_16x16x32_bf16(pf, vf, oacc[dt], 0, 0, 0);
      }
    }
  }

  bf16_t* ch = ctx + (size_t)bh * (SS * HDIM);
#pragma unroll
  for (int dt = 0; dt < 4; ++dt)
#pragma unroll
    for (int r = 0; r < 4; ++r)
      ch[(size_t)(qbase + quad * 4 + r) * HDIM + dt * 16 + lq] = f2b(oacc[dt][r]);
}

// ---------------- residual + LayerNorm over 768 ----------------
template <typename TR, typename TO>
__global__ __launch_bounds__(256) void ln_res_kernel(
    const bf16_t* __restrict__ a, const TR* __restrict__ res,
    const float* __restrict__ sc, const float* __restrict__ bi,
    TO* __restrict__ out) {
  __shared__ float red[8];
  const int row = blockIdx.x, tid = threadIdx.x;
  const size_t base = (size_t)row * DD;
  float v0 = b2f(a[base + tid]) + (float)res[base + tid];
  float v1 = b2f(a[base + 256 + tid]) + (float)res[base + 256 + tid];
  float v2 = b2f(a[base + 512 + tid]) + (float)res[base + 512 + tid];
  float s = v0 + v1 + v2;
#pragma unroll
  for (int o = 32; o; o >>= 1) s += __shfl_down(s, o, 64);
  if ((tid & 63) == 0) red[tid >> 6] = s;
  __syncthreads();
  const float mean = (red[0] + red[1] + red[2] + red[3]) * (1.f / 768.f);
  const float d0 = v0 - mean, d1 = v1 - mean, d2 = v2 - mean;
  float q = d0 * d0 + d1 * d1 + d2 * d2;
#pragma unroll
  for (int o = 32; o; o >>= 1) q += __shfl_down(q, o, 64);
  if ((tid & 63) == 0) red[4 + (tid >> 6)] = q;
  __syncthreads();
  const float var = (red[4] + red[5] + red[6] + red[7]) * (1.f / 768.f);
  const float rs = rsqrtf(var + 1e-6f);
  out[base + tid]       = (TO)(d0 * rs * sc[tid]       + bi[tid]);
  out[base + 256 + tid] = (TO)(d1 * rs * sc[256 + tid] + bi[256 + tid]);
  out[base + 512 + tid] = (TO)(d2 * rs * sc[512 + tid] + bi[512 + tid]);
}

extern "C" void kernel_launch(void* const* d_in, const int* in_sizes, int n_in,
                              void* d_out, int out_size, void* d_ws, size_t ws_size,
                              hipStream_t stream) {
  (void)in_sizes; (void)n_in; (void)out_size; (void)ws_size;
  const float* x    = (const float*)d_in[0];
  const float* mask = (const float*)d_in[1];
  const float* Wq = (const float*)d_in[2];
  const float* bq = (const float*)d_in[3];
  const float* Wk = (const float*)d_in[4];
  const float* bk = (const float*)d_in[5];
  const float* Wv = (const float*)d_in[6];
  const float* bv = (const float*)d_in[7];
  const float* Wo = (const float*)d_in[8];
  const float* bo = (const float*)d_in[9];
  const float* W1 = (const float*)d_in[10];
  const float* b1 = (const float*)d_in[11];
  const float* W2 = (const float*)d_in[12];
  const float* b2 = (const float*)d_in[13];
  const float* ln1s = (const float*)d_in[14];
  const float* ln1b = (const float*)d_in[15];
  const float* ln2s = (const float*)d_in[16];
  const float* ln2b = (const float*)d_in[17];
  float* out = (float*)d_out;
  float* attn_out = out + 3145728;  // x2 is 2*2048*768

  // bf16 workspace layout (element offsets); hb overlays kb/vb/ctx (dead by then)
  bf16_t* ws  = (bf16_t*)d_ws;
  bf16_t* wqT = ws;                     // 589824  (wq/wk/wv contiguous = fused 2304x768)
  bf16_t* wkT = wqT + 589824;
  bf16_t* wvT = wkT + 589824;
  bf16_t* woT = wvT + 589824;
  bf16_t* w1T = woT + 589824;           // 2359296
  bf16_t* w2T = w1T + 2359296;          // 2359296
  bf16_t* xb  = w2T + 2359296;          // 3145728
  bf16_t* x1  = xb  + 3145728;          // 3145728
  bf16_t* qb  = x1  + 3145728;          // 3145728
  bf16_t* kb  = qb  + 3145728;          // 3145728
  bf16_t* vb  = kb  + 3145728;          // 3145728
  bf16_t* ctx = vb  + 3145728;          // 3145728
  bf16_t* hb  = kb;                     // FFN hidden overlays kb/vb/ctx + tail
  bf16_t* att = qb;                     // reuse (q dead after attention)
  bf16_t* yb  = qb;                     // reuse (att dead after ln1)

  // single launch for all four 768x768 weight transposes (saves 3 dispatch gaps)
  transpose_cvt4x_kernel<<<dim3(24, 24, 4), 256, 0, stream>>>(Wq, Wk, Wv, Wo,
                                                              wqT, wkT, wvT, woT);
  transpose_cvt_kernel<<<dim3(96, 24), 256, 0, stream>>>(W1, w1T, 768, 3072);
  transpose_cvt_kernel<<<dim3(24, 96), 256, 0, stream>>>(W2, w2T, 3072, 768);
  cvt4_kernel<<<3072, 256, 0, stream>>>(x, xb, 786432);

  dim3 blk(256);
  gemm_bt<3, 128><<<dim3(32, 18), blk, 0, stream>>>(xb, wqT, nullptr, nullptr, MROWS, 2304, 768,
                                                    qb, kb, vb, bq, bk, bv);
  attn_kernel<<<768, blk, 0, stream>>>(qb, kb, vb, mask, attn_out, ctx);
  gemm_bt<0, 64><<<dim3(32, 12), blk, 0, stream>>>(ctx, woT, bo, att, MROWS, 768, 768,
                                                   nullptr, nullptr, nullptr, nullptr, nullptr, nullptr);
  ln_res_kernel<float, bf16_t><<<MROWS, blk, 0, stream>>>(att, x, ln1s, ln1b, x1);
  gemm_bt<2, 128><<<dim3(32, 24), blk, 0, stream>>>(x1, w1T, b1, hb, MROWS, FFD, 768,
                                                    nullptr, nullptr, nullptr, nullptr, nullptr, nullptr);
  gemm_bt<0, 64><<<dim3(32, 12), blk, 0, stream>>>(hb, w2T, b2, yb, MROWS, 768, FFD,
                                                   nullptr, nullptr, nullptr, nullptr, nullptr, nullptr);
  ln_res_kernel<bf16_t, float><<<MROWS, blk, 0, stream>>>(yb, x1, ln2s, ln2b, out);
}